// Round 5
// baseline (516.767 us; speedup 1.0000x reference)
//
#include <hip/hip_runtime.h>
#include <math.h>

#define CCH 256
#define NPOOL 7
#define NCLS 81
#define DCLS 80
#define NHEAD 512            /* padded head width: 81 logits + 324 reg + pad */
#define FLOG_MAX 4.1351666f  /* log(1000/16) */

typedef _Float16 half8 __attribute__((ext_vector_type(8)));
typedef _Float16 half4 __attribute__((ext_vector_type(4)));
typedef float floatx4 __attribute__((ext_vector_type(4)));

// ---------------------------------------------------------------------------
// zero a region (float4 stores)
// ---------------------------------------------------------------------------
__global__ void zero_k(float4* __restrict__ p, int count4)
{
    int i = blockIdx.x * blockDim.x + threadIdx.x;
    if (i < count4) p[i] = make_float4(0.f, 0.f, 0.f, 0.f);
}

// ---------------------------------------------------------------------------
// RoI-align box math (per-block scalar part)
// ---------------------------------------------------------------------------
__device__ __forceinline__ void roi_setup(
    const float* __restrict__ prop, const int* __restrict__ imidx,
    const float* __restrict__ f0, const float* __restrict__ f1,
    const float* __restrict__ f2, const float* __restrict__ f3,
    int h0, int h1, int h2, int h3, int b,
    const float*& base, int& W, size_t& o00, size_t& o01, size_t& o10, size_t& o11,
    float& w00, float& w01, float& w10, float& w11)
{
    int roi = b / 49, p = b % 49;
    int py = p / 7, px = p % 7;

    const float* pr = prop + (size_t)roi * 4;
    float x1 = pr[0], y1 = pr[1], x2 = pr[2], y2 = pr[3];
    float pw = x2 - x1, ph = y2 - y1;

    float lv = floorf(4.0f + log2f(sqrtf(pw * ph) / 224.0f + 1e-6f));
    lv = fminf(fmaxf(lv, 2.0f), 5.0f);
    int lvl = (int)lv - 2;

    const float* fm; int H; float s;
    if (lvl == 0)      { fm = f0; H = h0; s = 0.25f;    }
    else if (lvl == 1) { fm = f1; H = h1; s = 0.125f;   }
    else if (lvl == 2) { fm = f2; H = h2; s = 0.0625f;  }
    else               { fm = f3; H = h3; s = 0.03125f; }
    W = H;

    float xs1 = x1 * s, ys1 = y1 * s, xs2 = x2 * s, ys2 = y2 * s;
    float gx = (px + 0.5f) / 7.0f, gy = (py + 0.5f) / 7.0f;
    float xx = xs1 + gx * (xs2 - xs1) - 0.5f;
    float yy = ys1 + gy * (ys2 - ys1) - 0.5f;
    float x0f = floorf(xx), y0f = floorf(yy);
    float wx = xx - x0f, wy = yy - y0f;
    int x0i = min(max((int)x0f, 0), W - 1);
    int x1i = min(max((int)x0f + 1, 0), W - 1);
    int y0i = min(max((int)y0f, 0), H - 1);
    int y1i = min(max((int)y0f + 1, 0), H - 1);

    int ii = imidx[roi];
    base = fm + (size_t)ii * H * W * CCH;
    o00 = ((size_t)y0i * W + x0i) * CCH;
    o01 = ((size_t)y0i * W + x1i) * CCH;
    o10 = ((size_t)y1i * W + x0i) * CCH;
    o11 = ((size_t)y1i * W + x1i) * CCH;
    w00 = (1.0f - wx) * (1.0f - wy);
    w01 = wx * (1.0f - wy);
    w10 = (1.0f - wx) * wy;
    w11 = wx * wy;
}

// fp32 fallback variant: grid R*49 x 256 threads
__global__ void roi_align_k(const float* __restrict__ prop,
                            const int* __restrict__ imidx,
                            const float* __restrict__ f0,
                            const float* __restrict__ f1,
                            const float* __restrict__ f2,
                            const float* __restrict__ f3,
                            int h0, int h1, int h2, int h3,
                            float* __restrict__ pooled)
{
    int b = blockIdx.x, c = threadIdx.x;
    const float* base; int W; size_t o00, o01, o10, o11;
    float w00, w01, w10, w11;
    roi_setup(prop, imidx, f0, f1, f2, f3, h0, h1, h2, h3, b,
              base, W, o00, o01, o10, o11, w00, w01, w10, w11);
    float v = base[o00 + c] * w00 + base[o01 + c] * w01
            + base[o10 + c] * w10 + base[o11 + c] * w11;
    pooled[(size_t)b * CCH + c] = v;
}

// f16 hi/lo split, vectorized: grid R*49 x 64 threads (4 ch/thread)
__global__ __launch_bounds__(64) void roi_align_f16v_k(
    const float* __restrict__ prop, const int* __restrict__ imidx,
    const float* __restrict__ f0, const float* __restrict__ f1,
    const float* __restrict__ f2, const float* __restrict__ f3,
    int h0, int h1, int h2, int h3,
    _Float16* __restrict__ poolH, _Float16* __restrict__ poolL)
{
    int b = blockIdx.x;
    const float* base; int W; size_t o00, o01, o10, o11;
    float w00, w01, w10, w11;
    roi_setup(prop, imidx, f0, f1, f2, f3, h0, h1, h2, h3, b,
              base, W, o00, o01, o10, o11, w00, w01, w10, w11);

    int c4 = threadIdx.x * 4;
    float4 v00 = *(const float4*)(base + o00 + c4);
    float4 v01 = *(const float4*)(base + o01 + c4);
    float4 v10 = *(const float4*)(base + o10 + c4);
    float4 v11 = *(const float4*)(base + o11 + c4);
    const float* p00 = (const float*)&v00;
    const float* p01 = (const float*)&v01;
    const float* p10 = (const float*)&v10;
    const float* p11 = (const float*)&v11;

    half4 h, l;
#pragma unroll
    for (int e = 0; e < 4; ++e) {
        float v = p00[e] * w00 + p01[e] * w01 + p10[e] * w10 + p11[e] * w11;
        _Float16 hh = (_Float16)v;
        h[e] = hh;
        l[e] = (_Float16)(v - (float)hh);
    }
    size_t idx = (size_t)b * CCH + c4;
    *(half4*)(poolH + idx) = h;
    *(half4*)(poolL + idx) = l;
}

// ---------------------------------------------------------------------------
// Transpose-convert: W [K][N] fp32 -> WtH/WtL [N][K] f16 hi/lo.
// ---------------------------------------------------------------------------
__global__ __launch_bounds__(256) void convert_w_t_k(const float* __restrict__ W,
                                                     _Float16* __restrict__ WtH,
                                                     _Float16* __restrict__ WtL,
                                                     int K, int N)
{
    __shared__ float sh[64][65];
    int k0 = blockIdx.x * 64, n0 = blockIdx.y * 64;
    int t = threadIdx.x;
#pragma unroll
    for (int p = 0; p < 4; ++p) {
        int idx = p * 256 + t;
        int kr = idx >> 4, nc = (idx & 15) * 4;
        float4 v = *(const float4*)(W + (size_t)(k0 + kr) * N + n0 + nc);
        sh[kr][nc + 0] = v.x; sh[kr][nc + 1] = v.y;
        sh[kr][nc + 2] = v.z; sh[kr][nc + 3] = v.w;
    }
    __syncthreads();
#pragma unroll
    for (int p = 0; p < 4; ++p) {
        int idx = p * 256 + t;
        int nr = idx >> 4, kc = (idx & 15) * 4;
        half4 h, l;
#pragma unroll
        for (int i = 0; i < 4; ++i) {
            float v = sh[kc + i][nr];
            _Float16 hh = (_Float16)v;
            h[i] = hh;
            l[i] = (_Float16)(v - (float)hh);
        }
        *(half4*)(WtH + (size_t)(n0 + nr) * K + k0 + kc) = h;
        *(half4*)(WtL + (size_t)(n0 + nr) * K + k0 + kc) = l;
    }
}

// Guarded variant for N not multiple of 64; writes rows rowofs+n with stride Kt.
__global__ __launch_bounds__(256) void convert_w_t_guard_k(const float* __restrict__ W,
                                                           _Float16* __restrict__ WtH,
                                                           _Float16* __restrict__ WtL,
                                                           int K, int N, int Kt, int rowofs)
{
    __shared__ float sh[64][65];
    int k0 = blockIdx.x * 64, n0 = blockIdx.y * 64;
    int t = threadIdx.x;
#pragma unroll
    for (int p = 0; p < 4; ++p) {
        int idx = p * 256 + t;
        int kr = idx >> 4, nc = (idx & 15) * 4;
#pragma unroll
        for (int e = 0; e < 4; ++e) {
            int nn = n0 + nc + e;
            sh[kr][nc + e] = (nn < N) ? W[(size_t)(k0 + kr) * N + nn] : 0.0f;
        }
    }
    __syncthreads();
#pragma unroll
    for (int p = 0; p < 4; ++p) {
        int idx = p * 256 + t;
        int nr = idx >> 4, kc = (idx & 15) * 4;
        if (n0 + nr < N) {
            half4 h, l;
#pragma unroll
            for (int i = 0; i < 4; ++i) {
                float v = sh[kc + i][nr];
                _Float16 hh = (_Float16)v;
                h[i] = hh;
                l[i] = (_Float16)(v - (float)hh);
            }
            *(half4*)(WtH + (size_t)(rowofs + n0 + nr) * Kt + k0 + kc) = h;
            *(half4*)(WtL + (size_t)(rowofs + n0 + nr) * Kt + k0 + kc) = l;
        }
    }
}

// ---------------------------------------------------------------------------
// act-split: out = relu(acc + bias) -> f16 hi/lo. 4 elems/thread.
// ---------------------------------------------------------------------------
__global__ void act_split_k(const float* __restrict__ acc,
                            const float* __restrict__ bias,
                            _Float16* __restrict__ outH,
                            _Float16* __restrict__ outL,
                            int total, int CL)
{
    int i = (blockIdx.x * blockDim.x + threadIdx.x) * 4;
    if (i >= total) return;
    int b = i % CL;
    float4 v = *(const float4*)(acc + i);
    float4 bb = *(const float4*)(bias + b);
    const float* pv = (const float*)&v;
    const float* pb = (const float*)&bb;
    half4 h, l;
#pragma unroll
    for (int e = 0; e < 4; ++e) {
        float f = fmaxf(pv[e] + pb[e], 0.0f);
        _Float16 hh = (_Float16)f;
        h[e] = hh;
        l[e] = (_Float16)(f - (float)hh);
    }
    *(half4*)(outH + i) = h;
    *(half4*)(outL + i) = l;
}

// ---------------------------------------------------------------------------
// Split-f16 MFMA GEMM with distance-1 prefetch:
//   Cacc[M,N] += (Ah+Al)[M][K] @ (Bh+Bl)^T,  Bt given as [N][K].
// 128x128 block tile, BK=32, 256 thr (4 waves, 64x64 each).
// A: LDS double-buffered (stores placed AFTER the MFMA block so the global
//    loads issued one iteration earlier are ~900 cyc old at their vmcnt wait).
// B: register double-buffered (loaded one BK-step ahead, used after barrier).
// One __syncthreads per BK step. Split-K via blockIdx.z, fp32 atomicAdd
// epilogue. Requires M%128==0, N%128==0, (ke-kb)%64==0, Kc>=64.
// ---------------------------------------------------------------------------
#define LDK 36
#define ABUF (128 * LDK)

#define LOAD_A(kk)                                  \
    va0 = *(const half8*)(a0p + (kk));              \
    va1 = *(const half8*)(a1p + (kk));              \
    va2 = *(const half8*)(a2p + (kk));              \
    va3 = *(const half8*)(a3p + (kk));

#define STORE_A(sbuf)                                        \
    *(half8*)&sA[sbuf][srow * LDK + skq] = va0;              \
    *(half8*)&sA[sbuf][ABUF + srow * LDK + skq] = va1;       \
    *(half8*)&sA[sbuf][(srow + 64) * LDK + skq] = va2;       \
    *(half8*)&sA[sbuf][ABUF + (srow + 64) * LDK + skq] = va3;

#define LOAD_B(BH, BL, kk)                          \
    _Pragma("unroll")                               \
    for (int j = 0; j < 4; ++j) {                   \
        BH[j] = *(const half8*)(bhp[j] + (kk));     \
        BL[j] = *(const half8*)(blp[j] + (kk));     \
    }

#define MFMA_STEP(sbuf, BH, BL)                                                                       \
    {                                                                                                 \
        half8 ah[4], al[4];                                                                           \
        _Pragma("unroll")                                                                             \
        for (int i = 0; i < 4; ++i) {                                                                 \
            int ar = wr * 64 + i * 16 + fr;                                                           \
            ah[i] = *(const half8*)&sA[sbuf][ar * LDK + fk];                                          \
            al[i] = *(const half8*)&sA[sbuf][ABUF + ar * LDK + fk];                                   \
        }                                                                                             \
        _Pragma("unroll")                                                                             \
        for (int i = 0; i < 4; ++i)                                                                   \
            _Pragma("unroll")                                                                         \
            for (int j = 0; j < 4; ++j) {                                                             \
                acc[i][j] = __builtin_amdgcn_mfma_f32_16x16x32_f16(ah[i], BH[j], acc[i][j], 0, 0, 0); \
                acc[i][j] = __builtin_amdgcn_mfma_f32_16x16x32_f16(ah[i], BL[j], acc[i][j], 0, 0, 0); \
                acc[i][j] = __builtin_amdgcn_mfma_f32_16x16x32_f16(al[i], BH[j], acc[i][j], 0, 0, 0); \
            }                                                                                         \
    }

__global__ __launch_bounds__(256) void gemm_mfma_split_k(
    const _Float16* __restrict__ Ah, const _Float16* __restrict__ Al,
    const _Float16* __restrict__ Bh, const _Float16* __restrict__ Bl,
    float* __restrict__ Cacc, int M, int N, int K, int Kc)
{
    __shared__ _Float16 sA[2][2 * ABUF];   // [buf][ h | l ]

    int m0 = blockIdx.y * 128, n0 = blockIdx.x * 128;
    int kb = blockIdx.z * Kc;
    int ke = min(K, kb + Kc);
    int t = threadIdx.x;
    int lane = t & 63, w = t >> 6;
    int wr = w >> 1, wc = w & 1;          // 2x2 wave grid over 128x128
    int srow = t >> 2, skq = (t & 3) * 8; // A staging: 4 thr x 16B per row
    int fr = lane & 15;
    int fk = (lane >> 4) * 8;

    const _Float16* bhp[4];
    const _Float16* blp[4];
#pragma unroll
    for (int j = 0; j < 4; ++j) {
        int col = n0 + wc * 64 + j * 16 + fr;
        bhp[j] = Bh + (size_t)col * K + fk;
        blp[j] = Bl + (size_t)col * K + fk;
    }
    const _Float16* a0p = Ah + (size_t)(m0 + srow) * K + skq;
    const _Float16* a1p = Al + (size_t)(m0 + srow) * K + skq;
    const _Float16* a2p = a0p + (size_t)64 * K;
    const _Float16* a3p = a1p + (size_t)64 * K;

    floatx4 acc[4][4] = {};
    half8 va0, va1, va2, va3;
    half8 b0h[4], b0l[4], b1h[4], b1l[4];

    LOAD_A(kb)
    LOAD_B(b0h, b0l, kb)
    STORE_A(0)
    __syncthreads();

    for (int k0 = kb; k0 < ke; k0 += 64) {
        // ---- sub-step 0: compute k0 from buf0/set0; prefetch k0+32 ----
        LOAD_A(k0 + 32)                    // always valid: (ke-kb)%64==0
        LOAD_B(b1h, b1l, k0 + 32)
        MFMA_STEP(0, b0h, b0l)
        STORE_A(1)                         // vmcnt wait here: loads ~1 MFMA-block old
        __syncthreads();
        // ---- sub-step 1: compute k0+32 from buf1/set1; prefetch k0+64 ----
        if (k0 + 64 < ke) {
            LOAD_A(k0 + 64)
            LOAD_B(b0h, b0l, k0 + 64)
            MFMA_STEP(1, b1h, b1l)
            STORE_A(0)
        } else {
            MFMA_STEP(1, b1h, b1l)
        }
        __syncthreads();
    }

    // epilogue: C/D layout col=lane&15, row=(lane>>4)*4+reg
    int rbase = (lane >> 4) * 4;
#pragma unroll
    for (int i = 0; i < 4; ++i)
#pragma unroll
        for (int j = 0; j < 4; ++j) {
            int col = n0 + wc * 64 + j * 16 + fr;
#pragma unroll
            for (int r = 0; r < 4; ++r) {
                int row = m0 + wr * 64 + i * 16 + rbase + r;
                atomicAdd(&Cacc[(size_t)row * N + col], acc[i][j][r]);
            }
        }
}

// ---------------------------------------------------------------------------
// fp32 split-K GEMM (fallback path only)
// ---------------------------------------------------------------------------
__global__ __launch_bounds__(256) void gemm_splitk_k(const float* __restrict__ A,
                                                     const float* __restrict__ B,
                                                     const float* __restrict__ abias,
                                                     float* __restrict__ Cacc,
                                                     int M, int N, int K, int Kc)
{
    __shared__ float Ast[16][68];
    __shared__ float Bs[16][68];

    int m0 = blockIdx.y * 64, n0 = blockIdx.x * 64;
    int kb = blockIdx.z * Kc;
    int ke = min(K, kb + Kc);
    int tid = threadIdx.x;
    int tx = tid & 15, ty = tid >> 4;
    int arow = tid >> 2, akq = (tid & 3) << 2;
    int bcol = tid & 63, bk = tid >> 6;

    const float* Arow = A + (size_t)(m0 + arow) * K;
    bool nfull = (n0 + 64 <= N);

    float acc[4][4] = {};

    for (int k0 = kb; k0 < ke; k0 += 16) {
        float4 av = *(const float4*)(Arow + k0 + akq);
        if (abias) {
            av.x = fmaxf(av.x + abias[k0 + akq + 0], 0.0f);
            av.y = fmaxf(av.y + abias[k0 + akq + 1], 0.0f);
            av.z = fmaxf(av.z + abias[k0 + akq + 2], 0.0f);
            av.w = fmaxf(av.w + abias[k0 + akq + 3], 0.0f);
        }
        float bv[4];
        if (nfull) {
#pragma unroll
            for (int e = 0; e < 4; ++e)
                bv[e] = B[(size_t)(k0 + bk * 4 + e) * N + n0 + bcol];
        } else {
            bool ok = (n0 + bcol) < N;
#pragma unroll
            for (int e = 0; e < 4; ++e)
                bv[e] = ok ? B[(size_t)(k0 + bk * 4 + e) * N + n0 + bcol] : 0.0f;
        }
        __syncthreads();
        Ast[akq + 0][arow] = av.x;
        Ast[akq + 1][arow] = av.y;
        Ast[akq + 2][arow] = av.z;
        Ast[akq + 3][arow] = av.w;
#pragma unroll
        for (int e = 0; e < 4; ++e) Bs[bk * 4 + e][bcol] = bv[e];
        __syncthreads();

#pragma unroll
        for (int kk = 0; kk < 16; ++kk) {
            float4 af = *(const float4*)&Ast[kk][ty * 4];
            float4 bf = *(const float4*)&Bs[kk][tx * 4];
            float a_[4] = {af.x, af.y, af.z, af.w};
            float b_[4] = {bf.x, bf.y, bf.z, bf.w};
#pragma unroll
            for (int i = 0; i < 4; ++i)
#pragma unroll
                for (int j = 0; j < 4; ++j)
                    acc[i][j] = fmaf(a_[i], b_[j], acc[i][j]);
        }
    }

#pragma unroll
    for (int i = 0; i < 4; ++i) {
        int row = m0 + ty * 4 + i;
#pragma unroll
        for (int j = 0; j < 4; ++j) {
            int col = n0 + tx * 4 + j;
            if (col < N) atomicAdd(&Cacc[(size_t)row * N + col], acc[i][j]);
        }
    }
}

// ---------------------------------------------------------------------------
// softmax over (logits + bc), classes 1..80. grid = R, block = 64.
// ---------------------------------------------------------------------------
__global__ void softmax_k(const float* __restrict__ logits, int ldl,
                          const float* __restrict__ bc,
                          float* __restrict__ scr)
{
    int r = blockIdx.x;
    int t = threadIdx.x;
    const float* row = logits + (size_t)r * ldl;

    float v0 = row[t] + bc[t];
    float v1 = (t + 64 < NCLS) ? (row[t + 64] + bc[t + 64]) : -INFINITY;
    float m = fmaxf(v0, v1);
#pragma unroll
    for (int o = 32; o > 0; o >>= 1) m = fmaxf(m, __shfl_down(m, o));
    m = __shfl(m, 0);

    float e0 = expf(v0 - m);
    float e1 = (t + 64 < NCLS) ? expf(v1 - m) : 0.0f;
    float sum = e0 + e1;
#pragma unroll
    for (int o = 32; o > 0; o >>= 1) sum += __shfl_down(sum, o);
    sum = __shfl(sum, 0);
    float inv = 1.0f / sum;

    if (t >= 1)        scr[(size_t)r * DCLS + (t - 1)]  = e0 * inv;
    if (t + 64 < NCLS) scr[(size_t)r * DCLS + (t + 63)] = e1 * inv;
}

// ---------------------------------------------------------------------------
// per-image NMS with fused box decode. grid = n, block = 1024.
// Decode is computed only for score-passing candidates during compaction.
// reg value at head[r*ldh + regofs + cls*4 + e].
// ---------------------------------------------------------------------------
#define NMS_T 1024
__global__ __launch_bounds__(NMS_T) void nms_k(
    const float* __restrict__ scr,
    const float* __restrict__ prop,
    const int* __restrict__ imidx,
    const float* __restrict__ head, int ldh, int regofs,
    const float* __restrict__ br,
    const float* __restrict__ imsz,
    const float* __restrict__ score_thr_p,
    const float* __restrict__ min_size_p,
    const float* __restrict__ iou_thr_p,
    int* __restrict__ cidx,
    float* __restrict__ cscore,
    float* __restrict__ cbo,
    float* __restrict__ cbox,
    float* __restrict__ carea,
    float* __restrict__ out,
    int M, int n, int imtop)
{
    int img = blockIdx.x;
    int t = threadIdx.x;
    const int T = NMS_T;

    __shared__ int cnt;
    __shared__ float rs[NMS_T];
    __shared__ int rg[NMS_T];
    __shared__ int rl[NMS_T];
    __shared__ float wb0, wb1, wb2, wb3, wa;

    if (t == 0) cnt = 0;
    __syncthreads();

    float score_thr = score_thr_p[0];
    float min_size  = min_size_p[0];
    float iou_thr   = iou_thr_p[0];
    float immax = imsz[0];
    for (int q = 1; q < 2 * n; ++q) immax = fmaxf(immax, imsz[q]);

    int base = img * M;
    // compaction with fused decode
    for (int j = t; j < M; j += T) {
        int r = j / DCLS;
        if (imidx[r] != img) continue;
        float s = scr[j];
        if (s <= score_thr) continue;

        int cls = j - r * DCLS + 1;
        const float* pr = prop + (size_t)r * 4;
        float pw = pr[2] - pr[0], ph = pr[3] - pr[1];
        float cx = (pr[0] + pr[2]) * 0.5f, cy = (pr[1] + pr[3]) * 0.5f;
        const float* rg_ = head + (size_t)r * ldh + regofs + cls * 4;
        const float* bb = br + cls * 4;
        float dx = (rg_[0] + bb[0]) * 0.1f;
        float dy = (rg_[1] + bb[1]) * 0.1f;
        float dw = fminf((rg_[2] + bb[2]) * 0.2f, FLOG_MAX);
        float dh = fminf((rg_[3] + bb[3]) * 0.2f, FLOG_MAX);
        float ncx = dx * pw + cx;
        float ncy = dy * ph + cy;
        float nw = expf(dw) * pw;
        float nh = expf(dh) * ph;
        float hbound = imsz[img * 2 + 0];
        float wbound = imsz[img * 2 + 1];
        float bx1 = fminf(fmaxf(ncx - nw * 0.5f, 0.0f), wbound);
        float bx2 = fminf(fmaxf(ncx + nw * 0.5f, 0.0f), wbound);
        float by1 = fminf(fmaxf(ncy - nh * 0.5f, 0.0f), hbound);
        float by2 = fminf(fmaxf(ncy + nh * 0.5f, 0.0f), hbound);
        if (bx2 - bx1 < min_size || by2 - by1 < min_size) continue;

        float off = (float)cls * (immax + 2.0f);
        int p = atomicAdd(&cnt, 1);
        cidx[base + p] = j;
        cscore[base + p] = s;
        cbox[(size_t)(base + p) * 4 + 0] = bx1;
        cbox[(size_t)(base + p) * 4 + 1] = by1;
        cbox[(size_t)(base + p) * 4 + 2] = bx2;
        cbox[(size_t)(base + p) * 4 + 3] = by2;
        cbo[(size_t)(base + p) * 4 + 0] = bx1 + off;
        cbo[(size_t)(base + p) * 4 + 1] = by1 + off;
        cbo[(size_t)(base + p) * 4 + 2] = bx2 + off;
        cbo[(size_t)(base + p) * 4 + 3] = by2 + off;
        carea[base + p] = (bx2 - bx1) * (by2 - by1);
    }
    __syncthreads();
    int K = cnt;

    float* ob  = out;
    float* osc = out + (size_t)n * imtop * 4;
    float* ocl = out + (size_t)n * imtop * 5;

    int it = 0;
    for (; it < imtop; ++it) {
        float best = -1e30f; int bg = 0x7fffffff; int bl = -1;
        for (int p = t; p < K; p += T) {
            float sv = cscore[base + p];
            int g = cidx[base + p];
            if (sv > best || (sv == best && g < bg)) { best = sv; bg = g; bl = p; }
        }
        rs[t] = best; rg[t] = bg; rl[t] = bl;
        __syncthreads();
        for (int o = T / 2; o > 0; o >>= 1) {
            if (t < o) {
                if (rs[t + o] > rs[t] || (rs[t + o] == rs[t] && rg[t + o] < rg[t])) {
                    rs[t] = rs[t + o]; rg[t] = rg[t + o]; rl[t] = rl[t + o];
                }
            }
            __syncthreads();
        }
        float s = rs[0]; int g = rg[0]; int lp = rl[0];
        if (s <= 0.0f) break;

        if (t == 0) {
            size_t oslot = (size_t)img * imtop + it;
            ob[oslot * 4 + 0] = cbox[(size_t)(base + lp) * 4 + 0];
            ob[oslot * 4 + 1] = cbox[(size_t)(base + lp) * 4 + 1];
            ob[oslot * 4 + 2] = cbox[(size_t)(base + lp) * 4 + 2];
            ob[oslot * 4 + 3] = cbox[(size_t)(base + lp) * 4 + 3];
            osc[oslot] = s;
            ocl[oslot] = (float)(g % DCLS + 1);
            wb0 = cbo[(size_t)(base + lp) * 4 + 0];
            wb1 = cbo[(size_t)(base + lp) * 4 + 1];
            wb2 = cbo[(size_t)(base + lp) * 4 + 2];
            wb3 = cbo[(size_t)(base + lp) * 4 + 3];
            wa  = carea[base + lp];
            cscore[base + lp] = -1.0f;
        }
        __syncthreads();
        float b0 = wb0, b1 = wb1, b2 = wb2, b3 = wb3, ai = wa;
        for (int p = t; p < K; p += T) {
            float c0 = cbo[(size_t)(base + p) * 4 + 0];
            float c1 = cbo[(size_t)(base + p) * 4 + 1];
            float c2 = cbo[(size_t)(base + p) * 4 + 2];
            float c3 = cbo[(size_t)(base + p) * 4 + 3];
            float iw = fmaxf(fminf(b2, c2) - fmaxf(b0, c0), 0.0f);
            float ih = fmaxf(fminf(b3, c3) - fmaxf(b1, c1), 0.0f);
            float inter = iw * ih;
            float iou = inter / (ai + carea[base + p] - inter + 1e-6f);
            if (iou > iou_thr) cscore[base + p] = -1.0f;
        }
        __syncthreads();
    }

    for (int q = it + t; q < imtop; q += T) {
        size_t oslot = (size_t)img * imtop + q;
        ob[oslot * 4 + 0] = 0.0f;
        ob[oslot * 4 + 1] = 0.0f;
        ob[oslot * 4 + 2] = 0.0f;
        ob[oslot * 4 + 3] = 0.0f;
        osc[oslot] = 0.0f;
        ocl[oslot] = -1.0f;
    }
}

// ---------------------------------------------------------------------------
extern "C" void kernel_launch(void* const* d_in, const int* in_sizes, int n_in,
                              void* d_out, int out_size, void* d_ws, size_t ws_size,
                              hipStream_t stream)
{
    const float* prop   = (const float*)d_in[0];
    const int*   imidx  = (const int*)d_in[1];
    const float* f0     = (const float*)d_in[2];
    const float* f1     = (const float*)d_in[3];
    const float* f2     = (const float*)d_in[4];
    const float* f3     = (const float*)d_in[5];
    const float* W0     = (const float*)d_in[6];
    const float* b0     = (const float*)d_in[7];
    const float* W1     = (const float*)d_in[8];
    const float* b1     = (const float*)d_in[9];
    const float* Wc     = (const float*)d_in[10];
    const float* bc     = (const float*)d_in[11];
    const float* Wr     = (const float*)d_in[12];
    const float* br     = (const float*)d_in[13];
    const float* imsz   = (const float*)d_in[14];
    const float* sthr   = (const float*)d_in[15];
    const float* ithr   = (const float*)d_in[16];
    const float* msz    = (const float*)d_in[18];

    int R = in_sizes[1];              // 1024
    int n = in_sizes[14] / 2;         // 2
    int imtop = out_size / (n * 6);   // 100
    int M = R * DCLS;                 // 81920
    int K0 = NPOOL * NPOOL * CCH;     // 12544
    int CL = in_sizes[7];             // 1024

    int h0 = (int)(sqrtf((float)(in_sizes[2] / (n * CCH))) + 0.5f);
    int h1 = (int)(sqrtf((float)(in_sizes[3] / (n * CCH))) + 0.5f);
    int h2 = (int)(sqrtf((float)(in_sizes[4] / (n * CCH))) + 0.5f);
    int h3 = (int)(sqrtf((float)(in_sizes[5] / (n * CCH))) + 0.5f);

    float* outf = (float*)d_out;

    // ---- MFMA-path workspace layout (bytes) ----
    size_t szPool  = (size_t)R * K0 * 2;
    size_t szX     = (size_t)R * CL * 4;
    size_t szHead  = (size_t)R * NHEAD * 4;
    size_t szWh    = (size_t)NHEAD * CL * 2;
    size_t szXh    = (size_t)R * CL * 2;
    size_t szW1t   = (size_t)CL * CL * 2;
    size_t szScr   = (size_t)R * DCLS * 4;

    size_t needed = 4 * szPool + 2 * szX + szHead + 2 * szWh
                  + 4 * szXh + 2 * szW1t + szScr;

    int splitK0 = 14;                 // K0/14 = 896 = 14*64
    bool mfma_ok = (ws_size >= needed) && (R % 128 == 0) && (CL % 128 == 0)
                 && (K0 % (splitK0 * 64) == 0) && ((CL / 8) % 64 == 0);

    if (mfma_ok) {
        uint8_t* w = (uint8_t*)d_ws;
        size_t o = 0;
        _Float16* poolH   = (_Float16*)(w + o); o += szPool;
        _Float16* poolL   = (_Float16*)(w + o); o += szPool;
        _Float16* W0tH    = (_Float16*)(w + o); o += szPool;
        _Float16* W0tL    = (_Float16*)(w + o); o += szPool;
        float*    x0acc   = (float*)(w + o);    o += szX;
        float*    x1acc   = (float*)(w + o);    o += szX;
        float*    headacc = (float*)(w + o);    o += szHead;
        _Float16* WheadtH = (_Float16*)(w + o); o += szWh;
        _Float16* WheadtL = (_Float16*)(w + o); o += szWh;
        _Float16* x0H     = (_Float16*)(w + o); o += szXh;
        _Float16* x0L     = (_Float16*)(w + o); o += szXh;
        _Float16* x1H     = (_Float16*)(w + o); o += szXh;
        _Float16* x1L     = (_Float16*)(w + o); o += szXh;
        _Float16* W1tH    = (_Float16*)(w + o); o += szW1t;
        _Float16* W1tL    = (_Float16*)(w + o); o += szW1t;
        float*    scr     = (float*)(w + o);

        // NMS compaction arrays alias the pool region (dead after FC0)
        int*   cidx   = (int*)d_ws;
        float* cscore = (float*)(cidx + (size_t)n * M);
        float* cbo    = cscore + (size_t)n * M;
        float* cbox   = cbo + (size_t)n * M * 4;
        float* carea  = cbox + (size_t)n * M * 4;

        // 0. zero accumulators (x0acc, x1acc, headacc contiguous). Wheadt pad
        //    rows (>= NCLS*5) feed only headacc cols >= 405, which are never
        //    read -> no zeroing needed there.
        {
            size_t zbytes = 2 * szX + szHead;
            int c4 = (int)(zbytes / 16);
            zero_k<<<dim3((c4 + 255) / 256), dim3(256), 0, stream>>>((float4*)x0acc, c4);
        }
        // 1. weight converts
        convert_w_t_k<<<dim3(K0 / 64, CL / 64), dim3(256), 0, stream>>>(W0, W0tH, W0tL, K0, CL);
        convert_w_t_k<<<dim3(CL / 64, CL / 64), dim3(256), 0, stream>>>(W1, W1tH, W1tL, CL, CL);
        convert_w_t_guard_k<<<dim3(CL / 64, (NCLS + 63) / 64), dim3(256), 0, stream>>>(
            Wc, WheadtH, WheadtL, CL, NCLS, CL, 0);
        convert_w_t_guard_k<<<dim3(CL / 64, (NCLS * 4 + 63) / 64), dim3(256), 0, stream>>>(
            Wr, WheadtH, WheadtL, CL, NCLS * 4, CL, NCLS);
        // 2. RoI align -> f16 hi/lo pooled
        roi_align_f16v_k<<<dim3(R * 49), dim3(64), 0, stream>>>(
            prop, imidx, f0, f1, f2, f3, h0, h1, h2, h3, poolH, poolL);
        // 3. FC0: x0acc = pooled @ W0  (split-K 14, Kc=896)
        gemm_mfma_split_k<<<dim3(CL / 128, R / 128, splitK0), dim3(256), 0, stream>>>(
            poolH, poolL, W0tH, W0tL, x0acc, R, CL, K0, K0 / splitK0);
        // 4. x0 = relu(x0acc + b0) -> hi/lo
        act_split_k<<<dim3((R * CL / 4 + 255) / 256), dim3(256), 0, stream>>>(
            x0acc, b0, x0H, x0L, R * CL, CL);
        // 5. FC1: x1acc = x0 @ W1  (split-K 8, Kc=128)
        gemm_mfma_split_k<<<dim3(CL / 128, R / 128, 8), dim3(256), 0, stream>>>(
            x0H, x0L, W1tH, W1tL, x1acc, R, CL, CL, CL / 8);
        // 6. x1 = relu(x1acc + b1) -> hi/lo
        act_split_k<<<dim3((R * CL / 4 + 255) / 256), dim3(256), 0, stream>>>(
            x1acc, b1, x1H, x1L, R * CL, CL);
        // 7. combined heads: headacc = x1 @ [Wc|Wr]  (N=512 padded, split-K 8)
        gemm_mfma_split_k<<<dim3(NHEAD / 128, R / 128, 8), dim3(256), 0, stream>>>(
            x1H, x1L, WheadtH, WheadtL, headacc, R, NHEAD, CL, CL / 8);
        // 8. softmax (+bc)
        softmax_k<<<dim3(R), dim3(64), 0, stream>>>(headacc, NHEAD, bc, scr);
        // 9. NMS with fused decode (+br)
        nms_k<<<dim3(n), dim3(NMS_T), 0, stream>>>(
            scr, prop, imidx, headacc, NHEAD, NCLS, br, imsz, sthr, msz, ithr,
            cidx, cscore, cbo, cbox, carea, outf, M, n, imtop);
    } else {
        // -------- fallback: all-fp32 pipeline --------
        float* ws = (float*)d_ws;
        size_t off = 0;
        float* pooled  = ws + off; off += (size_t)R * K0;
        float* x0acc   = ws + off; off += (size_t)R * CL;
        float* x1acc   = ws + off; off += (size_t)R * CL;
        float* logits  = ws + off; off += (size_t)R * NCLS;
        off = (off + 3) & ~(size_t)3;
        float* reg     = ws + off; off += (size_t)R * NCLS * 4;
        float* scr     = ws + off; off += (size_t)R * DCLS;

        int*   cidx   = (int*)ws;
        float* cscore = (float*)(cidx + (size_t)n * M);
        float* cbo    = cscore + (size_t)n * M;
        float* cbox   = cbo + (size_t)n * M * 4;
        float* carea  = cbox + (size_t)n * M * 4;

        {
            size_t zcount = (size_t)(reg + (size_t)R * NCLS * 4 - x0acc);
            int c4 = (int)(zcount / 4);
            zero_k<<<dim3((c4 + 255) / 256), dim3(256), 0, stream>>>((float4*)x0acc, c4);
        }
        roi_align_k<<<dim3(R * 49), dim3(256), 0, stream>>>(
            prop, imidx, f0, f1, f2, f3, h0, h1, h2, h3, pooled);
        gemm_splitk_k<<<dim3(CL / 64, R / 64, 8), dim3(256), 0, stream>>>(
            pooled, W0, nullptr, x0acc, R, CL, K0, 1568);
        gemm_splitk_k<<<dim3(CL / 64, R / 64, 4), dim3(256), 0, stream>>>(
            x0acc, W1, b0, x1acc, R, CL, CL, 256);
        gemm_splitk_k<<<dim3((NCLS + 63) / 64, R / 64, 8), dim3(256), 0, stream>>>(
            x1acc, Wc, b1, logits, R, NCLS, CL, 128);
        gemm_splitk_k<<<dim3((NCLS * 4 + 63) / 64, R / 64, 4), dim3(256), 0, stream>>>(
            x1acc, Wr, b1, reg, R, NCLS * 4, CL, 256);
        softmax_k<<<dim3(R), dim3(64), 0, stream>>>(logits, NCLS, bc, scr);
        nms_k<<<dim3(n), dim3(NMS_T), 0, stream>>>(
            scr, prop, imidx, reg, NCLS * 4, 0, br, imsz, sthr, msz, ithr,
            cidx, cscore, cbo, cbox, carea, outf, M, n, imtop);
    }
}

// Round 6
// 466.006 us; speedup vs baseline: 1.1089x; 1.1089x over previous
//
#include <hip/hip_runtime.h>
#include <math.h>

#define CCH 256
#define NPOOL 7
#define NCLS 81
#define DCLS 80
#define NHEAD 512            /* padded head width: 81 logits + 324 reg + pad */
#define FLOG_MAX 4.1351666f  /* log(1000/16) */

typedef _Float16 half8 __attribute__((ext_vector_type(8)));
typedef _Float16 half4 __attribute__((ext_vector_type(4)));
typedef float floatx4 __attribute__((ext_vector_type(4)));

// ---------------------------------------------------------------------------
// zero a region (float4 stores)
// ---------------------------------------------------------------------------
__global__ void zero_k(float4* __restrict__ p, int count4)
{
    int i = blockIdx.x * blockDim.x + threadIdx.x;
    if (i < count4) p[i] = make_float4(0.f, 0.f, 0.f, 0.f);
}

// ---------------------------------------------------------------------------
// RoI-align box math (per-block scalar part)
// ---------------------------------------------------------------------------
__device__ __forceinline__ void roi_setup(
    const float* __restrict__ prop, const int* __restrict__ imidx,
    const float* __restrict__ f0, const float* __restrict__ f1,
    const float* __restrict__ f2, const float* __restrict__ f3,
    int h0, int h1, int h2, int h3, int b,
    const float*& base, int& W, size_t& o00, size_t& o01, size_t& o10, size_t& o11,
    float& w00, float& w01, float& w10, float& w11)
{
    int roi = b / 49, p = b % 49;
    int py = p / 7, px = p % 7;

    const float* pr = prop + (size_t)roi * 4;
    float x1 = pr[0], y1 = pr[1], x2 = pr[2], y2 = pr[3];
    float pw = x2 - x1, ph = y2 - y1;

    float lv = floorf(4.0f + log2f(sqrtf(pw * ph) / 224.0f + 1e-6f));
    lv = fminf(fmaxf(lv, 2.0f), 5.0f);
    int lvl = (int)lv - 2;

    const float* fm; int H; float s;
    if (lvl == 0)      { fm = f0; H = h0; s = 0.25f;    }
    else if (lvl == 1) { fm = f1; H = h1; s = 0.125f;   }
    else if (lvl == 2) { fm = f2; H = h2; s = 0.0625f;  }
    else               { fm = f3; H = h3; s = 0.03125f; }
    W = H;

    float xs1 = x1 * s, ys1 = y1 * s, xs2 = x2 * s, ys2 = y2 * s;
    float gx = (px + 0.5f) / 7.0f, gy = (py + 0.5f) / 7.0f;
    float xx = xs1 + gx * (xs2 - xs1) - 0.5f;
    float yy = ys1 + gy * (ys2 - ys1) - 0.5f;
    float x0f = floorf(xx), y0f = floorf(yy);
    float wx = xx - x0f, wy = yy - y0f;
    int x0i = min(max((int)x0f, 0), W - 1);
    int x1i = min(max((int)x0f + 1, 0), W - 1);
    int y0i = min(max((int)y0f, 0), H - 1);
    int y1i = min(max((int)y0f + 1, 0), H - 1);

    int ii = imidx[roi];
    base = fm + (size_t)ii * H * W * CCH;
    o00 = ((size_t)y0i * W + x0i) * CCH;
    o01 = ((size_t)y0i * W + x1i) * CCH;
    o10 = ((size_t)y1i * W + x0i) * CCH;
    o11 = ((size_t)y1i * W + x1i) * CCH;
    w00 = (1.0f - wx) * (1.0f - wy);
    w01 = wx * (1.0f - wy);
    w10 = (1.0f - wx) * wy;
    w11 = wx * wy;
}

// fp32 fallback variant: grid R*49 x 256 threads
__global__ void roi_align_k(const float* __restrict__ prop,
                            const int* __restrict__ imidx,
                            const float* __restrict__ f0,
                            const float* __restrict__ f1,
                            const float* __restrict__ f2,
                            const float* __restrict__ f3,
                            int h0, int h1, int h2, int h3,
                            float* __restrict__ pooled)
{
    int b = blockIdx.x, c = threadIdx.x;
    const float* base; int W; size_t o00, o01, o10, o11;
    float w00, w01, w10, w11;
    roi_setup(prop, imidx, f0, f1, f2, f3, h0, h1, h2, h3, b,
              base, W, o00, o01, o10, o11, w00, w01, w10, w11);
    float v = base[o00 + c] * w00 + base[o01 + c] * w01
            + base[o10 + c] * w10 + base[o11 + c] * w11;
    pooled[(size_t)b * CCH + c] = v;
}

// f16 hi/lo split, vectorized: grid R*49 x 64 threads (4 ch/thread)
__global__ __launch_bounds__(64) void roi_align_f16v_k(
    const float* __restrict__ prop, const int* __restrict__ imidx,
    const float* __restrict__ f0, const float* __restrict__ f1,
    const float* __restrict__ f2, const float* __restrict__ f3,
    int h0, int h1, int h2, int h3,
    _Float16* __restrict__ poolH, _Float16* __restrict__ poolL)
{
    int b = blockIdx.x;
    const float* base; int W; size_t o00, o01, o10, o11;
    float w00, w01, w10, w11;
    roi_setup(prop, imidx, f0, f1, f2, f3, h0, h1, h2, h3, b,
              base, W, o00, o01, o10, o11, w00, w01, w10, w11);

    int c4 = threadIdx.x * 4;
    float4 v00 = *(const float4*)(base + o00 + c4);
    float4 v01 = *(const float4*)(base + o01 + c4);
    float4 v10 = *(const float4*)(base + o10 + c4);
    float4 v11 = *(const float4*)(base + o11 + c4);
    const float* p00 = (const float*)&v00;
    const float* p01 = (const float*)&v01;
    const float* p10 = (const float*)&v10;
    const float* p11 = (const float*)&v11;

    half4 h, l;
#pragma unroll
    for (int e = 0; e < 4; ++e) {
        float v = p00[e] * w00 + p01[e] * w01 + p10[e] * w10 + p11[e] * w11;
        _Float16 hh = (_Float16)v;
        h[e] = hh;
        l[e] = (_Float16)(v - (float)hh);
    }
    size_t idx = (size_t)b * CCH + c4;
    *(half4*)(poolH + idx) = h;
    *(half4*)(poolL + idx) = l;
}

// ---------------------------------------------------------------------------
// Transpose-convert: W [K][N] fp32 -> WtH/WtL [N][K] f16 hi/lo.
// ---------------------------------------------------------------------------
__global__ __launch_bounds__(256) void convert_w_t_k(const float* __restrict__ W,
                                                     _Float16* __restrict__ WtH,
                                                     _Float16* __restrict__ WtL,
                                                     int K, int N)
{
    __shared__ float sh[64][65];
    int k0 = blockIdx.x * 64, n0 = blockIdx.y * 64;
    int t = threadIdx.x;
#pragma unroll
    for (int p = 0; p < 4; ++p) {
        int idx = p * 256 + t;
        int kr = idx >> 4, nc = (idx & 15) * 4;
        float4 v = *(const float4*)(W + (size_t)(k0 + kr) * N + n0 + nc);
        sh[kr][nc + 0] = v.x; sh[kr][nc + 1] = v.y;
        sh[kr][nc + 2] = v.z; sh[kr][nc + 3] = v.w;
    }
    __syncthreads();
#pragma unroll
    for (int p = 0; p < 4; ++p) {
        int idx = p * 256 + t;
        int nr = idx >> 4, kc = (idx & 15) * 4;
        half4 h, l;
#pragma unroll
        for (int i = 0; i < 4; ++i) {
            float v = sh[kc + i][nr];
            _Float16 hh = (_Float16)v;
            h[i] = hh;
            l[i] = (_Float16)(v - (float)hh);
        }
        *(half4*)(WtH + (size_t)(n0 + nr) * K + k0 + kc) = h;
        *(half4*)(WtL + (size_t)(n0 + nr) * K + k0 + kc) = l;
    }
}

// Guarded variant for N not multiple of 64; writes rows rowofs+n with stride Kt.
__global__ __launch_bounds__(256) void convert_w_t_guard_k(const float* __restrict__ W,
                                                           _Float16* __restrict__ WtH,
                                                           _Float16* __restrict__ WtL,
                                                           int K, int N, int Kt, int rowofs)
{
    __shared__ float sh[64][65];
    int k0 = blockIdx.x * 64, n0 = blockIdx.y * 64;
    int t = threadIdx.x;
#pragma unroll
    for (int p = 0; p < 4; ++p) {
        int idx = p * 256 + t;
        int kr = idx >> 4, nc = (idx & 15) * 4;
#pragma unroll
        for (int e = 0; e < 4; ++e) {
            int nn = n0 + nc + e;
            sh[kr][nc + e] = (nn < N) ? W[(size_t)(k0 + kr) * N + nn] : 0.0f;
        }
    }
    __syncthreads();
#pragma unroll
    for (int p = 0; p < 4; ++p) {
        int idx = p * 256 + t;
        int nr = idx >> 4, kc = (idx & 15) * 4;
        if (n0 + nr < N) {
            half4 h, l;
#pragma unroll
            for (int i = 0; i < 4; ++i) {
                float v = sh[kc + i][nr];
                _Float16 hh = (_Float16)v;
                h[i] = hh;
                l[i] = (_Float16)(v - (float)hh);
            }
            *(half4*)(WtH + (size_t)(rowofs + n0 + nr) * Kt + k0 + kc) = h;
            *(half4*)(WtL + (size_t)(rowofs + n0 + nr) * Kt + k0 + kc) = l;
        }
    }
}

// ---------------------------------------------------------------------------
// act-split: out = relu(acc + bias) -> f16 hi/lo. 4 elems/thread.
// ---------------------------------------------------------------------------
__global__ void act_split_k(const float* __restrict__ acc,
                            const float* __restrict__ bias,
                            _Float16* __restrict__ outH,
                            _Float16* __restrict__ outL,
                            int total, int CL)
{
    int i = (blockIdx.x * blockDim.x + threadIdx.x) * 4;
    if (i >= total) return;
    int b = i % CL;
    float4 v = *(const float4*)(acc + i);
    float4 bb = *(const float4*)(bias + b);
    const float* pv = (const float*)&v;
    const float* pb = (const float*)&bb;
    half4 h, l;
#pragma unroll
    for (int e = 0; e < 4; ++e) {
        float f = fmaxf(pv[e] + pb[e], 0.0f);
        _Float16 hh = (_Float16)f;
        h[e] = hh;
        l[e] = (_Float16)(f - (float)hh);
    }
    *(half4*)(outH + i) = h;
    *(half4*)(outL + i) = l;
}

// ---------------------------------------------------------------------------
// Split-f16 MFMA GEMM, m97-style async staging:
//   Cacc[M,N] += (Ah+Al)[M][K] @ (Bh+Bl)^T,  Bt given as [N][K].
// 128x128 block tile, BK=32, 256 thr (4 waves, 64x64 each = 4x4 of
// 16x16x32 f16 MFMA, 3 products). All four tiles (A/B hi/lo) staged via
// __builtin_amdgcn_global_load_lds width=16 (no VGPR round-trip; the
// barrier's vmcnt(0) drain is the only wait). LDS unpadded (LDK=32, DMA
// dest = wave-uniform base + lane*16); fragment ds_read_b128 then aliases
// max 2-way per quarter-wave (free per m136). Split-K via blockIdx.z,
// fp32 atomicAdd epilogue (Cacc pre-zeroed).
// Requires M%128==0, N%128==0, Kc%32==0.
// ---------------------------------------------------------------------------
#define LDKE 32   /* halves per LDS row (64 B), unpadded for DMA */

__device__ __forceinline__ void dma16(const _Float16* g, _Float16* l)
{
    __builtin_amdgcn_global_load_lds(
        (const __attribute__((address_space(1))) unsigned int*)g,
        (__attribute__((address_space(3))) unsigned int*)l, 16, 0, 0);
}

__global__ __launch_bounds__(256) void gemm_mfma_split_k(
    const _Float16* __restrict__ Ah, const _Float16* __restrict__ Al,
    const _Float16* __restrict__ Bh, const _Float16* __restrict__ Bl,
    float* __restrict__ Cacc, int M, int N, int K, int Kc)
{
    __shared__ _Float16 sAh[128 * LDKE], sAl[128 * LDKE];
    __shared__ _Float16 sBh[128 * LDKE], sBl[128 * LDKE];

    int m0 = blockIdx.y * 128, n0 = blockIdx.x * 128;
    int kb = blockIdx.z * Kc;
    int ke = min(K, kb + Kc);
    int t = threadIdx.x;
    int lane = t & 63, w = t >> 6;
    int wr = w >> 1, wc = w & 1;          // 2x2 wave grid over 128x128
    int fr = lane & 15;                   // fragment row/col within 16
    int fk = (lane >> 4) * 8;             // fragment k offset (quad*8)

    // DMA mapping: wave w stages row-chunks {2w, 2w+1} (16 rows x 32 halves
    // = 1 KB each) of every array. Lane L -> row_local = L>>2, kq = (L&3)*8.
    int drow = w * 32 + (lane >> 2);      // chunk 2w row; chunk 2w+1 adds 16
    int dkq = (lane & 3) * 8;
    const _Float16* gAh = Ah + (size_t)(m0 + drow) * K + dkq;
    const _Float16* gAl = Al + (size_t)(m0 + drow) * K + dkq;
    const _Float16* gBh = Bh + (size_t)(n0 + drow) * K + dkq;
    const _Float16* gBl = Bl + (size_t)(n0 + drow) * K + dkq;
    size_t rowskip = (size_t)16 * K;      // chunk 2w+1 global offset

    // wave-uniform LDS bases (halves): chunk c at (w*2+c)*512
    _Float16* lAh0 = &sAh[(w * 2 + 0) * 512];
    _Float16* lAh1 = &sAh[(w * 2 + 1) * 512];
    _Float16* lAl0 = &sAl[(w * 2 + 0) * 512];
    _Float16* lAl1 = &sAl[(w * 2 + 1) * 512];
    _Float16* lBh0 = &sBh[(w * 2 + 0) * 512];
    _Float16* lBh1 = &sBh[(w * 2 + 1) * 512];
    _Float16* lBl0 = &sBl[(w * 2 + 0) * 512];
    _Float16* lBl1 = &sBl[(w * 2 + 1) * 512];

    floatx4 acc[4][4] = {};

    for (int k0 = kb; k0 < ke; k0 += 32) {
        dma16(gAh + k0, lAh0);
        dma16(gAh + rowskip + k0, lAh1);
        dma16(gAl + k0, lAl0);
        dma16(gAl + rowskip + k0, lAl1);
        dma16(gBh + k0, lBh0);
        dma16(gBh + rowskip + k0, lBh1);
        dma16(gBl + k0, lBl0);
        dma16(gBl + rowskip + k0, lBl1);
        __syncthreads();   // drains vmcnt -> DMA data visible

        half8 ah[4], al[4], bh[4], bl[4];
#pragma unroll
        for (int i = 0; i < 4; ++i) {
            int ar = wr * 64 + i * 16 + fr;
            ah[i] = *(const half8*)&sAh[ar * LDKE + fk];
            al[i] = *(const half8*)&sAl[ar * LDKE + fk];
            int bc = wc * 64 + i * 16 + fr;
            bh[i] = *(const half8*)&sBh[bc * LDKE + fk];
            bl[i] = *(const half8*)&sBl[bc * LDKE + fk];
        }
#pragma unroll
        for (int i = 0; i < 4; ++i)
#pragma unroll
            for (int j = 0; j < 4; ++j) {
                acc[i][j] = __builtin_amdgcn_mfma_f32_16x16x32_f16(ah[i], bh[j], acc[i][j], 0, 0, 0);
                acc[i][j] = __builtin_amdgcn_mfma_f32_16x16x32_f16(ah[i], bl[j], acc[i][j], 0, 0, 0);
                acc[i][j] = __builtin_amdgcn_mfma_f32_16x16x32_f16(al[i], bh[j], acc[i][j], 0, 0, 0);
            }
        __syncthreads();   // LDS reads complete before next DMA overwrite
    }

    // epilogue: C/D layout col=lane&15, row=(lane>>4)*4+reg
    int rbase = (lane >> 4) * 4;
#pragma unroll
    for (int i = 0; i < 4; ++i)
#pragma unroll
        for (int j = 0; j < 4; ++j) {
            int col = n0 + wc * 64 + j * 16 + fr;
#pragma unroll
            for (int r = 0; r < 4; ++r) {
                int row = m0 + wr * 64 + i * 16 + rbase + r;
                atomicAdd(&Cacc[(size_t)row * N + col], acc[i][j][r]);
            }
        }
}

// ---------------------------------------------------------------------------
// fp32 split-K GEMM (fallback path only)
// ---------------------------------------------------------------------------
__global__ __launch_bounds__(256) void gemm_splitk_k(const float* __restrict__ A,
                                                     const float* __restrict__ B,
                                                     const float* __restrict__ abias,
                                                     float* __restrict__ Cacc,
                                                     int M, int N, int K, int Kc)
{
    __shared__ float Ast[16][68];
    __shared__ float Bs[16][68];

    int m0 = blockIdx.y * 64, n0 = blockIdx.x * 64;
    int kb = blockIdx.z * Kc;
    int ke = min(K, kb + Kc);
    int tid = threadIdx.x;
    int tx = tid & 15, ty = tid >> 4;
    int arow = tid >> 2, akq = (tid & 3) << 2;
    int bcol = tid & 63, bk = tid >> 6;

    const float* Arow = A + (size_t)(m0 + arow) * K;
    bool nfull = (n0 + 64 <= N);

    float acc[4][4] = {};

    for (int k0 = kb; k0 < ke; k0 += 16) {
        float4 av = *(const float4*)(Arow + k0 + akq);
        if (abias) {
            av.x = fmaxf(av.x + abias[k0 + akq + 0], 0.0f);
            av.y = fmaxf(av.y + abias[k0 + akq + 1], 0.0f);
            av.z = fmaxf(av.z + abias[k0 + akq + 2], 0.0f);
            av.w = fmaxf(av.w + abias[k0 + akq + 3], 0.0f);
        }
        float bv[4];
        if (nfull) {
#pragma unroll
            for (int e = 0; e < 4; ++e)
                bv[e] = B[(size_t)(k0 + bk * 4 + e) * N + n0 + bcol];
        } else {
            bool ok = (n0 + bcol) < N;
#pragma unroll
            for (int e = 0; e < 4; ++e)
                bv[e] = ok ? B[(size_t)(k0 + bk * 4 + e) * N + n0 + bcol] : 0.0f;
        }
        __syncthreads();
        Ast[akq + 0][arow] = av.x;
        Ast[akq + 1][arow] = av.y;
        Ast[akq + 2][arow] = av.z;
        Ast[akq + 3][arow] = av.w;
#pragma unroll
        for (int e = 0; e < 4; ++e) Bs[bk * 4 + e][bcol] = bv[e];
        __syncthreads();

#pragma unroll
        for (int kk = 0; kk < 16; ++kk) {
            float4 af = *(const float4*)&Ast[kk][ty * 4];
            float4 bf = *(const float4*)&Bs[kk][tx * 4];
            float a_[4] = {af.x, af.y, af.z, af.w};
            float b_[4] = {bf.x, bf.y, bf.z, bf.w};
#pragma unroll
            for (int i = 0; i < 4; ++i)
#pragma unroll
                for (int j = 0; j < 4; ++j)
                    acc[i][j] = fmaf(a_[i], b_[j], acc[i][j]);
        }
    }

#pragma unroll
    for (int i = 0; i < 4; ++i) {
        int row = m0 + ty * 4 + i;
#pragma unroll
        for (int j = 0; j < 4; ++j) {
            int col = n0 + tx * 4 + j;
            if (col < N) atomicAdd(&Cacc[(size_t)row * N + col], acc[i][j]);
        }
    }
}

// ---------------------------------------------------------------------------
// softmax over (logits + bc), classes 1..80. grid = R, block = 64.
// ---------------------------------------------------------------------------
__global__ void softmax_k(const float* __restrict__ logits, int ldl,
                          const float* __restrict__ bc,
                          float* __restrict__ scr)
{
    int r = blockIdx.x;
    int t = threadIdx.x;
    const float* row = logits + (size_t)r * ldl;

    float v0 = row[t] + bc[t];
    float v1 = (t + 64 < NCLS) ? (row[t + 64] + bc[t + 64]) : -INFINITY;
    float m = fmaxf(v0, v1);
#pragma unroll
    for (int o = 32; o > 0; o >>= 1) m = fmaxf(m, __shfl_down(m, o));
    m = __shfl(m, 0);

    float e0 = expf(v0 - m);
    float e1 = (t + 64 < NCLS) ? expf(v1 - m) : 0.0f;
    float sum = e0 + e1;
#pragma unroll
    for (int o = 32; o > 0; o >>= 1) sum += __shfl_down(sum, o);
    sum = __shfl(sum, 0);
    float inv = 1.0f / sum;

    if (t >= 1)        scr[(size_t)r * DCLS + (t - 1)]  = e0 * inv;
    if (t + 64 < NCLS) scr[(size_t)r * DCLS + (t + 63)] = e1 * inv;
}

// ---------------------------------------------------------------------------
// per-image NMS with fused box decode. grid = n, block = 1024.
// ---------------------------------------------------------------------------
#define NMS_T 1024
__global__ __launch_bounds__(NMS_T) void nms_k(
    const float* __restrict__ scr,
    const float* __restrict__ prop,
    const int* __restrict__ imidx,
    const float* __restrict__ head, int ldh, int regofs,
    const float* __restrict__ br,
    const float* __restrict__ imsz,
    const float* __restrict__ score_thr_p,
    const float* __restrict__ min_size_p,
    const float* __restrict__ iou_thr_p,
    int* __restrict__ cidx,
    float* __restrict__ cscore,
    float* __restrict__ cbo,
    float* __restrict__ cbox,
    float* __restrict__ carea,
    float* __restrict__ out,
    int M, int n, int imtop)
{
    int img = blockIdx.x;
    int t = threadIdx.x;
    const int T = NMS_T;

    __shared__ int cnt;
    __shared__ float rs[NMS_T];
    __shared__ int rg[NMS_T];
    __shared__ int rl[NMS_T];
    __shared__ float wb0, wb1, wb2, wb3, wa;

    if (t == 0) cnt = 0;
    __syncthreads();

    float score_thr = score_thr_p[0];
    float min_size  = min_size_p[0];
    float iou_thr   = iou_thr_p[0];
    float immax = imsz[0];
    for (int q = 1; q < 2 * n; ++q) immax = fmaxf(immax, imsz[q]);

    int base = img * M;
    // compaction with fused decode
    for (int j = t; j < M; j += T) {
        int r = j / DCLS;
        if (imidx[r] != img) continue;
        float s = scr[j];
        if (s <= score_thr) continue;

        int cls = j - r * DCLS + 1;
        const float* pr = prop + (size_t)r * 4;
        float pw = pr[2] - pr[0], ph = pr[3] - pr[1];
        float cx = (pr[0] + pr[2]) * 0.5f, cy = (pr[1] + pr[3]) * 0.5f;
        const float* rg_ = head + (size_t)r * ldh + regofs + cls * 4;
        const float* bb = br + cls * 4;
        float dx = (rg_[0] + bb[0]) * 0.1f;
        float dy = (rg_[1] + bb[1]) * 0.1f;
        float dw = fminf((rg_[2] + bb[2]) * 0.2f, FLOG_MAX);
        float dh = fminf((rg_[3] + bb[3]) * 0.2f, FLOG_MAX);
        float ncx = dx * pw + cx;
        float ncy = dy * ph + cy;
        float nw = expf(dw) * pw;
        float nh = expf(dh) * ph;
        float hbound = imsz[img * 2 + 0];
        float wbound = imsz[img * 2 + 1];
        float bx1 = fminf(fmaxf(ncx - nw * 0.5f, 0.0f), wbound);
        float bx2 = fminf(fmaxf(ncx + nw * 0.5f, 0.0f), wbound);
        float by1 = fminf(fmaxf(ncy - nh * 0.5f, 0.0f), hbound);
        float by2 = fminf(fmaxf(ncy + nh * 0.5f, 0.0f), hbound);
        if (bx2 - bx1 < min_size || by2 - by1 < min_size) continue;

        float off = (float)cls * (immax + 2.0f);
        int p = atomicAdd(&cnt, 1);
        cidx[base + p] = j;
        cscore[base + p] = s;
        cbox[(size_t)(base + p) * 4 + 0] = bx1;
        cbox[(size_t)(base + p) * 4 + 1] = by1;
        cbox[(size_t)(base + p) * 4 + 2] = bx2;
        cbox[(size_t)(base + p) * 4 + 3] = by2;
        cbo[(size_t)(base + p) * 4 + 0] = bx1 + off;
        cbo[(size_t)(base + p) * 4 + 1] = by1 + off;
        cbo[(size_t)(base + p) * 4 + 2] = bx2 + off;
        cbo[(size_t)(base + p) * 4 + 3] = by2 + off;
        carea[base + p] = (bx2 - bx1) * (by2 - by1);
    }
    __syncthreads();
    int K = cnt;

    float* ob  = out;
    float* osc = out + (size_t)n * imtop * 4;
    float* ocl = out + (size_t)n * imtop * 5;

    int it = 0;
    for (; it < imtop; ++it) {
        float best = -1e30f; int bg = 0x7fffffff; int bl = -1;
        for (int p = t; p < K; p += T) {
            float sv = cscore[base + p];
            int g = cidx[base + p];
            if (sv > best || (sv == best && g < bg)) { best = sv; bg = g; bl = p; }
        }
        rs[t] = best; rg[t] = bg; rl[t] = bl;
        __syncthreads();
        for (int o = T / 2; o > 0; o >>= 1) {
            if (t < o) {
                if (rs[t + o] > rs[t] || (rs[t + o] == rs[t] && rg[t + o] < rg[t])) {
                    rs[t] = rs[t + o]; rg[t] = rg[t + o]; rl[t] = rl[t + o];
                }
            }
            __syncthreads();
        }
        float s = rs[0]; int g = rg[0]; int lp = rl[0];
        if (s <= 0.0f) break;

        if (t == 0) {
            size_t oslot = (size_t)img * imtop + it;
            ob[oslot * 4 + 0] = cbox[(size_t)(base + lp) * 4 + 0];
            ob[oslot * 4 + 1] = cbox[(size_t)(base + lp) * 4 + 1];
            ob[oslot * 4 + 2] = cbox[(size_t)(base + lp) * 4 + 2];
            ob[oslot * 4 + 3] = cbox[(size_t)(base + lp) * 4 + 3];
            osc[oslot] = s;
            ocl[oslot] = (float)(g % DCLS + 1);
            wb0 = cbo[(size_t)(base + lp) * 4 + 0];
            wb1 = cbo[(size_t)(base + lp) * 4 + 1];
            wb2 = cbo[(size_t)(base + lp) * 4 + 2];
            wb3 = cbo[(size_t)(base + lp) * 4 + 3];
            wa  = carea[base + lp];
            cscore[base + lp] = -1.0f;
        }
        __syncthreads();
        float b0 = wb0, b1 = wb1, b2 = wb2, b3 = wb3, ai = wa;
        for (int p = t; p < K; p += T) {
            float c0 = cbo[(size_t)(base + p) * 4 + 0];
            float c1 = cbo[(size_t)(base + p) * 4 + 1];
            float c2 = cbo[(size_t)(base + p) * 4 + 2];
            float c3 = cbo[(size_t)(base + p) * 4 + 3];
            float iw = fmaxf(fminf(b2, c2) - fmaxf(b0, c0), 0.0f);
            float ih = fmaxf(fminf(b3, c3) - fmaxf(b1, c1), 0.0f);
            float inter = iw * ih;
            float iou = inter / (ai + carea[base + p] - inter + 1e-6f);
            if (iou > iou_thr) cscore[base + p] = -1.0f;
        }
        __syncthreads();
    }

    for (int q = it + t; q < imtop; q += T) {
        size_t oslot = (size_t)img * imtop + q;
        ob[oslot * 4 + 0] = 0.0f;
        ob[oslot * 4 + 1] = 0.0f;
        ob[oslot * 4 + 2] = 0.0f;
        ob[oslot * 4 + 3] = 0.0f;
        osc[oslot] = 0.0f;
        ocl[oslot] = -1.0f;
    }
}

// ---------------------------------------------------------------------------
extern "C" void kernel_launch(void* const* d_in, const int* in_sizes, int n_in,
                              void* d_out, int out_size, void* d_ws, size_t ws_size,
                              hipStream_t stream)
{
    const float* prop   = (const float*)d_in[0];
    const int*   imidx  = (const int*)d_in[1];
    const float* f0     = (const float*)d_in[2];
    const float* f1     = (const float*)d_in[3];
    const float* f2     = (const float*)d_in[4];
    const float* f3     = (const float*)d_in[5];
    const float* W0     = (const float*)d_in[6];
    const float* b0     = (const float*)d_in[7];
    const float* W1     = (const float*)d_in[8];
    const float* b1     = (const float*)d_in[9];
    const float* Wc     = (const float*)d_in[10];
    const float* bc     = (const float*)d_in[11];
    const float* Wr     = (const float*)d_in[12];
    const float* br     = (const float*)d_in[13];
    const float* imsz   = (const float*)d_in[14];
    const float* sthr   = (const float*)d_in[15];
    const float* ithr   = (const float*)d_in[16];
    const float* msz    = (const float*)d_in[18];

    int R = in_sizes[1];              // 1024
    int n = in_sizes[14] / 2;         // 2
    int imtop = out_size / (n * 6);   // 100
    int M = R * DCLS;                 // 81920
    int K0 = NPOOL * NPOOL * CCH;     // 12544
    int CL = in_sizes[7];             // 1024

    int h0 = (int)(sqrtf((float)(in_sizes[2] / (n * CCH))) + 0.5f);
    int h1 = (int)(sqrtf((float)(in_sizes[3] / (n * CCH))) + 0.5f);
    int h2 = (int)(sqrtf((float)(in_sizes[4] / (n * CCH))) + 0.5f);
    int h3 = (int)(sqrtf((float)(in_sizes[5] / (n * CCH))) + 0.5f);

    float* outf = (float*)d_out;

    // ---- MFMA-path workspace layout (bytes) ----
    size_t szPool  = (size_t)R * K0 * 2;
    size_t szX     = (size_t)R * CL * 4;
    size_t szHead  = (size_t)R * NHEAD * 4;
    size_t szWh    = (size_t)NHEAD * CL * 2;
    size_t szXh    = (size_t)R * CL * 2;
    size_t szW1t   = (size_t)CL * CL * 2;
    size_t szScr   = (size_t)R * DCLS * 4;

    size_t needed = 4 * szPool + 2 * szX + szHead + 2 * szWh
                  + 4 * szXh + 2 * szW1t + szScr;

    int splitK0 = 14;                 // K0/14 = 896
    bool mfma_ok = (ws_size >= needed) && (R % 128 == 0) && (CL % 128 == 0)
                 && (K0 % (splitK0 * 32) == 0) && ((CL / 8) % 32 == 0);

    if (mfma_ok) {
        uint8_t* w = (uint8_t*)d_ws;
        size_t o = 0;
        _Float16* poolH   = (_Float16*)(w + o); o += szPool;
        _Float16* poolL   = (_Float16*)(w + o); o += szPool;
        _Float16* W0tH    = (_Float16*)(w + o); o += szPool;
        _Float16* W0tL    = (_Float16*)(w + o); o += szPool;
        float*    x0acc   = (float*)(w + o);    o += szX;
        float*    x1acc   = (float*)(w + o);    o += szX;
        float*    headacc = (float*)(w + o);    o += szHead;
        _Float16* WheadtH = (_Float16*)(w + o); o += szWh;
        _Float16* WheadtL = (_Float16*)(w + o); o += szWh;
        _Float16* x0H     = (_Float16*)(w + o); o += szXh;
        _Float16* x0L     = (_Float16*)(w + o); o += szXh;
        _Float16* x1H     = (_Float16*)(w + o); o += szXh;
        _Float16* x1L     = (_Float16*)(w + o); o += szXh;
        _Float16* W1tH    = (_Float16*)(w + o); o += szW1t;
        _Float16* W1tL    = (_Float16*)(w + o); o += szW1t;
        float*    scr     = (float*)(w + o);

        // NMS compaction arrays alias the pool region (dead after FC0)
        int*   cidx   = (int*)d_ws;
        float* cscore = (float*)(cidx + (size_t)n * M);
        float* cbo    = cscore + (size_t)n * M;
        float* cbox   = cbo + (size_t)n * M * 4;
        float* carea  = cbox + (size_t)n * M * 4;

        // 0. zero accumulators (x0acc, x1acc, headacc contiguous)
        {
            size_t zbytes = 2 * szX + szHead;
            int c4 = (int)(zbytes / 16);
            zero_k<<<dim3((c4 + 255) / 256), dim3(256), 0, stream>>>((float4*)x0acc, c4);
        }
        // 1. weight converts
        convert_w_t_k<<<dim3(K0 / 64, CL / 64), dim3(256), 0, stream>>>(W0, W0tH, W0tL, K0, CL);
        convert_w_t_k<<<dim3(CL / 64, CL / 64), dim3(256), 0, stream>>>(W1, W1tH, W1tL, CL, CL);
        convert_w_t_guard_k<<<dim3(CL / 64, (NCLS + 63) / 64), dim3(256), 0, stream>>>(
            Wc, WheadtH, WheadtL, CL, NCLS, CL, 0);
        convert_w_t_guard_k<<<dim3(CL / 64, (NCLS * 4 + 63) / 64), dim3(256), 0, stream>>>(
            Wr, WheadtH, WheadtL, CL, NCLS * 4, CL, NCLS);
        // 2. RoI align -> f16 hi/lo pooled
        roi_align_f16v_k<<<dim3(R * 49), dim3(64), 0, stream>>>(
            prop, imidx, f0, f1, f2, f3, h0, h1, h2, h3, poolH, poolL);
        // 3. FC0: x0acc = pooled @ W0  (split-K 14, Kc=896)
        gemm_mfma_split_k<<<dim3(CL / 128, R / 128, splitK0), dim3(256), 0, stream>>>(
            poolH, poolL, W0tH, W0tL, x0acc, R, CL, K0, K0 / splitK0);
        // 4. x0 = relu(x0acc + b0) -> hi/lo
        act_split_k<<<dim3((R * CL / 4 + 255) / 256), dim3(256), 0, stream>>>(
            x0acc, b0, x0H, x0L, R * CL, CL);
        // 5. FC1: x1acc = x0 @ W1  (split-K 8, Kc=128)
        gemm_mfma_split_k<<<dim3(CL / 128, R / 128, 8), dim3(256), 0, stream>>>(
            x0H, x0L, W1tH, W1tL, x1acc, R, CL, CL, CL / 8);
        // 6. x1 = relu(x1acc + b1) -> hi/lo
        act_split_k<<<dim3((R * CL / 4 + 255) / 256), dim3(256), 0, stream>>>(
            x1acc, b1, x1H, x1L, R * CL, CL);
        // 7. combined heads: headacc = x1 @ [Wc|Wr]  (N=512 padded, split-K 8)
        gemm_mfma_split_k<<<dim3(NHEAD / 128, R / 128, 8), dim3(256), 0, stream>>>(
            x1H, x1L, WheadtH, WheadtL, headacc, R, NHEAD, CL, CL / 8);
        // 8. softmax (+bc)
        softmax_k<<<dim3(R), dim3(64), 0, stream>>>(headacc, NHEAD, bc, scr);
        // 9. NMS with fused decode (+br)
        nms_k<<<dim3(n), dim3(NMS_T), 0, stream>>>(
            scr, prop, imidx, headacc, NHEAD, NCLS, br, imsz, sthr, msz, ithr,
            cidx, cscore, cbo, cbox, carea, outf, M, n, imtop);
    } else {
        // -------- fallback: all-fp32 pipeline --------
        float* ws = (float*)d_ws;
        size_t off = 0;
        float* pooled  = ws + off; off += (size_t)R * K0;
        float* x0acc   = ws + off; off += (size_t)R * CL;
        float* x1acc   = ws + off; off += (size_t)R * CL;
        float* logits  = ws + off; off += (size_t)R * NCLS;
        off = (off + 3) & ~(size_t)3;
        float* reg     = ws + off; off += (size_t)R * NCLS * 4;
        float* scr     = ws + off; off += (size_t)R * DCLS;

        int*   cidx   = (int*)ws;
        float* cscore = (float*)(cidx + (size_t)n * M);
        float* cbo    = cscore + (size_t)n * M;
        float* cbox   = cbo + (size_t)n * M * 4;
        float* carea  = cbox + (size_t)n * M * 4;

        {
            size_t zcount = (size_t)(reg + (size_t)R * NCLS * 4 - x0acc);
            int c4 = (int)(zcount / 4);
            zero_k<<<dim3((c4 + 255) / 256), dim3(256), 0, stream>>>((float4*)x0acc, c4);
        }
        roi_align_k<<<dim3(R * 49), dim3(256), 0, stream>>>(
            prop, imidx, f0, f1, f2, f3, h0, h1, h2, h3, pooled);
        gemm_splitk_k<<<dim3(CL / 64, R / 64, 8), dim3(256), 0, stream>>>(
            pooled, W0, nullptr, x0acc, R, CL, K0, 1568);
        gemm_splitk_k<<<dim3(CL / 64, R / 64, 4), dim3(256), 0, stream>>>(
            x0acc, W1, b0, x1acc, R, CL, CL, 256);
        gemm_splitk_k<<<dim3((NCLS + 63) / 64, R / 64, 8), dim3(256), 0, stream>>>(
            x1acc, Wc, b1, logits, R, NCLS, CL, 128);
        gemm_splitk_k<<<dim3((NCLS * 4 + 63) / 64, R / 64, 4), dim3(256), 0, stream>>>(
            x1acc, Wr, b1, reg, R, NCLS * 4, CL, 256);
        softmax_k<<<dim3(R), dim3(64), 0, stream>>>(logits, NCLS, bc, scr);
        nms_k<<<dim3(n), dim3(NMS_T), 0, stream>>>(
            scr, prop, imidx, reg, NCLS * 4, 0, br, imsz, sthr, msz, ithr,
            cidx, cscore, cbo, cbox, carea, outf, M, n, imtop);
    }
}

// Round 7
// 421.857 us; speedup vs baseline: 1.2250x; 1.1047x over previous
//
#include <hip/hip_runtime.h>
#include <math.h>

#define CCH 256
#define NPOOL 7
#define NCLS 81
#define DCLS 80
#define NHEAD 512            /* padded head width: 81 logits + 324 reg + pad */
#define FLOG_MAX 4.1351666f  /* log(1000/16) */

typedef _Float16 half8 __attribute__((ext_vector_type(8)));
typedef _Float16 half4 __attribute__((ext_vector_type(4)));
typedef float floatx4 __attribute__((ext_vector_type(4)));

// ---------------------------------------------------------------------------
// zero a region (float4 stores)
// ---------------------------------------------------------------------------
__global__ void zero_k(float4* __restrict__ p, int count4)
{
    int i = blockIdx.x * blockDim.x + threadIdx.x;
    if (i < count4) p[i] = make_float4(0.f, 0.f, 0.f, 0.f);
}

// ---------------------------------------------------------------------------
// RoI-align box math (per-cell scalar part)
// ---------------------------------------------------------------------------
__device__ __forceinline__ void roi_setup(
    const float* __restrict__ prop, const int* __restrict__ imidx,
    const float* __restrict__ f0, const float* __restrict__ f1,
    const float* __restrict__ f2, const float* __restrict__ f3,
    int h0, int h1, int h2, int h3, int b,
    const float*& base, int& W, size_t& o00, size_t& o01, size_t& o10, size_t& o11,
    float& w00, float& w01, float& w10, float& w11)
{
    int roi = b / 49, p = b % 49;
    int py = p / 7, px = p % 7;

    const float* pr = prop + (size_t)roi * 4;
    float x1 = pr[0], y1 = pr[1], x2 = pr[2], y2 = pr[3];
    float pw = x2 - x1, ph = y2 - y1;

    float lv = floorf(4.0f + log2f(sqrtf(pw * ph) / 224.0f + 1e-6f));
    lv = fminf(fmaxf(lv, 2.0f), 5.0f);
    int lvl = (int)lv - 2;

    const float* fm; int H; float s;
    if (lvl == 0)      { fm = f0; H = h0; s = 0.25f;    }
    else if (lvl == 1) { fm = f1; H = h1; s = 0.125f;   }
    else if (lvl == 2) { fm = f2; H = h2; s = 0.0625f;  }
    else               { fm = f3; H = h3; s = 0.03125f; }
    W = H;

    float xs1 = x1 * s, ys1 = y1 * s, xs2 = x2 * s, ys2 = y2 * s;
    float gx = (px + 0.5f) / 7.0f, gy = (py + 0.5f) / 7.0f;
    float xx = xs1 + gx * (xs2 - xs1) - 0.5f;
    float yy = ys1 + gy * (ys2 - ys1) - 0.5f;
    float x0f = floorf(xx), y0f = floorf(yy);
    float wx = xx - x0f, wy = yy - y0f;
    int x0i = min(max((int)x0f, 0), W - 1);
    int x1i = min(max((int)x0f + 1, 0), W - 1);
    int y0i = min(max((int)y0f, 0), H - 1);
    int y1i = min(max((int)y0f + 1, 0), H - 1);

    int ii = imidx[roi];
    base = fm + (size_t)ii * H * W * CCH;
    o00 = ((size_t)y0i * W + x0i) * CCH;
    o01 = ((size_t)y0i * W + x1i) * CCH;
    o10 = ((size_t)y1i * W + x0i) * CCH;
    o11 = ((size_t)y1i * W + x1i) * CCH;
    w00 = (1.0f - wx) * (1.0f - wy);
    w01 = wx * (1.0f - wy);
    w10 = (1.0f - wx) * wy;
    w11 = wx * wy;
}

// fp32 fallback variant: grid R*49 x 256 threads
__global__ void roi_align_k(const float* __restrict__ prop,
                            const int* __restrict__ imidx,
                            const float* __restrict__ f0,
                            const float* __restrict__ f1,
                            const float* __restrict__ f2,
                            const float* __restrict__ f3,
                            int h0, int h1, int h2, int h3,
                            float* __restrict__ pooled)
{
    int b = blockIdx.x, c = threadIdx.x;
    const float* base; int W; size_t o00, o01, o10, o11;
    float w00, w01, w10, w11;
    roi_setup(prop, imidx, f0, f1, f2, f3, h0, h1, h2, h3, b,
              base, W, o00, o01, o10, o11, w00, w01, w10, w11);
    float v = base[o00 + c] * w00 + base[o01 + c] * w01
            + base[o10 + c] * w10 + base[o11 + c] * w11;
    pooled[(size_t)b * CCH + c] = v;
}

// f16 hi/lo split: grid R*49/4 blocks x 256 threads; wave w -> cell 4b+w
__global__ __launch_bounds__(256) void roi_align_f16v4_k(
    const float* __restrict__ prop, const int* __restrict__ imidx,
    const float* __restrict__ f0, const float* __restrict__ f1,
    const float* __restrict__ f2, const float* __restrict__ f3,
    int h0, int h1, int h2, int h3,
    _Float16* __restrict__ poolH, _Float16* __restrict__ poolL)
{
    int b = blockIdx.x * 4 + (threadIdx.x >> 6);
    int lane = threadIdx.x & 63;
    const float* base; int W; size_t o00, o01, o10, o11;
    float w00, w01, w10, w11;
    roi_setup(prop, imidx, f0, f1, f2, f3, h0, h1, h2, h3, b,
              base, W, o00, o01, o10, o11, w00, w01, w10, w11);

    int c4 = lane * 4;
    float4 v00 = *(const float4*)(base + o00 + c4);
    float4 v01 = *(const float4*)(base + o01 + c4);
    float4 v10 = *(const float4*)(base + o10 + c4);
    float4 v11 = *(const float4*)(base + o11 + c4);
    const float* p00 = (const float*)&v00;
    const float* p01 = (const float*)&v01;
    const float* p10 = (const float*)&v10;
    const float* p11 = (const float*)&v11;

    half4 h, l;
#pragma unroll
    for (int e = 0; e < 4; ++e) {
        float v = p00[e] * w00 + p01[e] * w01 + p10[e] * w10 + p11[e] * w11;
        _Float16 hh = (_Float16)v;
        h[e] = hh;
        l[e] = (_Float16)(v - (float)hh);
    }
    size_t idx = (size_t)b * CCH + c4;
    *(half4*)(poolH + idx) = h;
    *(half4*)(poolL + idx) = l;
}

// ---------------------------------------------------------------------------
// Transpose-convert: W [K][N] fp32 -> WtH/WtL [N][K] f16 hi/lo.
// ---------------------------------------------------------------------------
__global__ __launch_bounds__(256) void convert_w_t_k(const float* __restrict__ W,
                                                     _Float16* __restrict__ WtH,
                                                     _Float16* __restrict__ WtL,
                                                     int K, int N)
{
    __shared__ float sh[64][65];
    int k0 = blockIdx.x * 64, n0 = blockIdx.y * 64;
    int t = threadIdx.x;
#pragma unroll
    for (int p = 0; p < 4; ++p) {
        int idx = p * 256 + t;
        int kr = idx >> 4, nc = (idx & 15) * 4;
        float4 v = *(const float4*)(W + (size_t)(k0 + kr) * N + n0 + nc);
        sh[kr][nc + 0] = v.x; sh[kr][nc + 1] = v.y;
        sh[kr][nc + 2] = v.z; sh[kr][nc + 3] = v.w;
    }
    __syncthreads();
#pragma unroll
    for (int p = 0; p < 4; ++p) {
        int idx = p * 256 + t;
        int nr = idx >> 4, kc = (idx & 15) * 4;
        half4 h, l;
#pragma unroll
        for (int i = 0; i < 4; ++i) {
            float v = sh[kc + i][nr];
            _Float16 hh = (_Float16)v;
            h[i] = hh;
            l[i] = (_Float16)(v - (float)hh);
        }
        *(half4*)(WtH + (size_t)(n0 + nr) * K + k0 + kc) = h;
        *(half4*)(WtL + (size_t)(n0 + nr) * K + k0 + kc) = l;
    }
}

// Guarded variant for N not multiple of 64; writes rows rowofs+n with stride Kt.
__global__ __launch_bounds__(256) void convert_w_t_guard_k(const float* __restrict__ W,
                                                           _Float16* __restrict__ WtH,
                                                           _Float16* __restrict__ WtL,
                                                           int K, int N, int Kt, int rowofs)
{
    __shared__ float sh[64][65];
    int k0 = blockIdx.x * 64, n0 = blockIdx.y * 64;
    int t = threadIdx.x;
#pragma unroll
    for (int p = 0; p < 4; ++p) {
        int idx = p * 256 + t;
        int kr = idx >> 4, nc = (idx & 15) * 4;
#pragma unroll
        for (int e = 0; e < 4; ++e) {
            int nn = n0 + nc + e;
            sh[kr][nc + e] = (nn < N) ? W[(size_t)(k0 + kr) * N + nn] : 0.0f;
        }
    }
    __syncthreads();
#pragma unroll
    for (int p = 0; p < 4; ++p) {
        int idx = p * 256 + t;
        int nr = idx >> 4, kc = (idx & 15) * 4;
        if (n0 + nr < N) {
            half4 h, l;
#pragma unroll
            for (int i = 0; i < 4; ++i) {
                float v = sh[kc + i][nr];
                _Float16 hh = (_Float16)v;
                h[i] = hh;
                l[i] = (_Float16)(v - (float)hh);
            }
            *(half4*)(WtH + (size_t)(rowofs + n0 + nr) * Kt + k0 + kc) = h;
            *(half4*)(WtL + (size_t)(rowofs + n0 + nr) * Kt + k0 + kc) = l;
        }
    }
}

// ---------------------------------------------------------------------------
// act-split: out = relu(acc + bias) -> f16 hi/lo. 4 elems/thread.
// ---------------------------------------------------------------------------
__global__ void act_split_k(const float* __restrict__ acc,
                            const float* __restrict__ bias,
                            _Float16* __restrict__ outH,
                            _Float16* __restrict__ outL,
                            int total, int CL)
{
    int i = (blockIdx.x * blockDim.x + threadIdx.x) * 4;
    if (i >= total) return;
    int b = i % CL;
    float4 v = *(const float4*)(acc + i);
    float4 bb = *(const float4*)(bias + b);
    const float* pv = (const float*)&v;
    const float* pb = (const float*)&bb;
    half4 h, l;
#pragma unroll
    for (int e = 0; e < 4; ++e) {
        float f = fmaxf(pv[e] + pb[e], 0.0f);
        _Float16 hh = (_Float16)f;
        h[e] = hh;
        l[e] = (_Float16)(f - (float)hh);
    }
    *(half4*)(outH + i) = h;
    *(half4*)(outL + i) = l;
}

// ---------------------------------------------------------------------------
// global->LDS DMA, width 16 (wave-uniform LDS base + lane*16)
// ---------------------------------------------------------------------------
__device__ __forceinline__ void dma16(const _Float16* g, _Float16* l)
{
    __builtin_amdgcn_global_load_lds(
        (const __attribute__((address_space(1))) unsigned int*)g,
        (__attribute__((address_space(3))) unsigned int*)l, 16, 0, 0);
}

// ---------------------------------------------------------------------------
// Split-f16 MFMA GEMM, DMA staging, XCD-pinned 1-D grid:
//   Cacc[M,N] += (Ah+Al)[M][K] @ (Bh+Bl)^T,  Bt given as [N][K].
// 128x128 block tile, BK=32, 256 thr (4 waves, 64x64 each).
// 1-D grid of SP*(M/128)*(N/128); decode z = bid%SP (-> XCD via the
// bid%8 round-robin heuristic: all blocks of one K-slice share an XCD's
// L2), n fastest (A-panel reuse), m slowest. fp32 atomicAdd epilogue.
// Requires M%128==0, N%128==0, Kc%32==0.
// ---------------------------------------------------------------------------
#define LDKE 32   /* halves per LDS row (64 B), unpadded for DMA */

__global__ __launch_bounds__(256) void gemm_mfma_split_k(
    const _Float16* __restrict__ Ah, const _Float16* __restrict__ Al,
    const _Float16* __restrict__ Bh, const _Float16* __restrict__ Bl,
    float* __restrict__ Cacc, int M, int N, int K, int Kc, int SP)
{
    __shared__ _Float16 sAh[128 * LDKE], sAl[128 * LDKE];
    __shared__ _Float16 sBh[128 * LDKE], sBl[128 * LDKE];

    int bid = blockIdx.x;
    int z = bid % SP;
    int q = bid / SP;
    int NT = N >> 7;
    int nn = q % NT;
    int m = q / NT;
    int m0 = m * 128, n0 = nn * 128;
    int kb = z * Kc;
    int ke = min(K, kb + Kc);

    int t = threadIdx.x;
    int lane = t & 63, w = t >> 6;
    int wr = w >> 1, wc = w & 1;          // 2x2 wave grid over 128x128
    int fr = lane & 15;                   // fragment row/col within 16
    int fk = (lane >> 4) * 8;             // fragment k offset (quad*8)

    // DMA mapping: wave w stages row-chunks {2w, 2w+1} (16 rows x 32 halves
    // = 1 KB each) of every array. Lane L -> row_local = L>>2, kq = (L&3)*8.
    int drow = w * 32 + (lane >> 2);
    int dkq = (lane & 3) * 8;
    const _Float16* gAh = Ah + (size_t)(m0 + drow) * K + dkq;
    const _Float16* gAl = Al + (size_t)(m0 + drow) * K + dkq;
    const _Float16* gBh = Bh + (size_t)(n0 + drow) * K + dkq;
    const _Float16* gBl = Bl + (size_t)(n0 + drow) * K + dkq;
    size_t rowskip = (size_t)16 * K;

    _Float16* lAh0 = &sAh[(w * 2 + 0) * 512];
    _Float16* lAh1 = &sAh[(w * 2 + 1) * 512];
    _Float16* lAl0 = &sAl[(w * 2 + 0) * 512];
    _Float16* lAl1 = &sAl[(w * 2 + 1) * 512];
    _Float16* lBh0 = &sBh[(w * 2 + 0) * 512];
    _Float16* lBh1 = &sBh[(w * 2 + 1) * 512];
    _Float16* lBl0 = &sBl[(w * 2 + 0) * 512];
    _Float16* lBl1 = &sBl[(w * 2 + 1) * 512];

    floatx4 acc[4][4] = {};

    for (int k0 = kb; k0 < ke; k0 += 32) {
        dma16(gAh + k0, lAh0);
        dma16(gAh + rowskip + k0, lAh1);
        dma16(gAl + k0, lAl0);
        dma16(gAl + rowskip + k0, lAl1);
        dma16(gBh + k0, lBh0);
        dma16(gBh + rowskip + k0, lBh1);
        dma16(gBl + k0, lBl0);
        dma16(gBl + rowskip + k0, lBl1);
        __syncthreads();   // drains vmcnt -> DMA data visible

        half8 ah[4], al[4], bh[4], bl[4];
#pragma unroll
        for (int i = 0; i < 4; ++i) {
            int ar = wr * 64 + i * 16 + fr;
            ah[i] = *(const half8*)&sAh[ar * LDKE + fk];
            al[i] = *(const half8*)&sAl[ar * LDKE + fk];
            int bc = wc * 64 + i * 16 + fr;
            bh[i] = *(const half8*)&sBh[bc * LDKE + fk];
            bl[i] = *(const half8*)&sBl[bc * LDKE + fk];
        }
#pragma unroll
        for (int i = 0; i < 4; ++i)
#pragma unroll
            for (int j = 0; j < 4; ++j) {
                acc[i][j] = __builtin_amdgcn_mfma_f32_16x16x32_f16(ah[i], bh[j], acc[i][j], 0, 0, 0);
                acc[i][j] = __builtin_amdgcn_mfma_f32_16x16x32_f16(ah[i], bl[j], acc[i][j], 0, 0, 0);
                acc[i][j] = __builtin_amdgcn_mfma_f32_16x16x32_f16(al[i], bh[j], acc[i][j], 0, 0, 0);
            }
        __syncthreads();   // LDS reads complete before next DMA overwrite
    }

    // epilogue: C/D layout col=lane&15, row=(lane>>4)*4+reg
    int rbase = (lane >> 4) * 4;
#pragma unroll
    for (int i = 0; i < 4; ++i)
#pragma unroll
        for (int j = 0; j < 4; ++j) {
            int col = n0 + wc * 64 + j * 16 + fr;
#pragma unroll
            for (int r = 0; r < 4; ++r) {
                int row = m0 + wr * 64 + i * 16 + rbase + r;
                atomicAdd(&Cacc[(size_t)row * N + col], acc[i][j][r]);
            }
        }
}

// ---------------------------------------------------------------------------
// Non-split fused MFMA GEMM, 64x64 tile, full-K accumulation in registers:
//   C = (Ah+Al) @ (Bh+Bl)^T   (3 products)
// mode 0: Cout[row*N+col] = C (raw fp32)
// mode 1: relu(C + bias[col]) -> outH/outL f16 hi/lo
// 256 thr (2x2 waves of 32x32 = 2x2 of 16x16x32). DMA staging (16 KB LDS).
// Requires M%64==0, N%64==0, K%32==0.
// ---------------------------------------------------------------------------
__global__ __launch_bounds__(256) void gemm_mfma_fused64_k(
    const _Float16* __restrict__ Ah, const _Float16* __restrict__ Al,
    const _Float16* __restrict__ Bh, const _Float16* __restrict__ Bl,
    const float* __restrict__ bias,
    float* __restrict__ Cout,
    _Float16* __restrict__ outH, _Float16* __restrict__ outL,
    int M, int N, int K, int mode)
{
    __shared__ _Float16 sAh[64 * LDKE], sAl[64 * LDKE];
    __shared__ _Float16 sBh[64 * LDKE], sBl[64 * LDKE];

    int m0 = blockIdx.y * 64, n0 = blockIdx.x * 64;
    int t = threadIdx.x;
    int lane = t & 63, w = t >> 6;
    int wr = w >> 1, wc = w & 1;          // 2x2 wave grid over 64x64
    int fr = lane & 15;
    int fk = (lane >> 4) * 8;

    // DMA: wave w stages rows [w*16, w*16+16) of all four arrays
    int drow = w * 16 + (lane >> 2);
    int dkq = (lane & 3) * 8;
    const _Float16* gAh = Ah + (size_t)(m0 + drow) * K + dkq;
    const _Float16* gAl = Al + (size_t)(m0 + drow) * K + dkq;
    const _Float16* gBh = Bh + (size_t)(n0 + drow) * K + dkq;
    const _Float16* gBl = Bl + (size_t)(n0 + drow) * K + dkq;
    _Float16* lAh = &sAh[w * 512];
    _Float16* lAl = &sAl[w * 512];
    _Float16* lBh = &sBh[w * 512];
    _Float16* lBl = &sBl[w * 512];

    floatx4 acc[2][2] = {};

    for (int k0 = 0; k0 < K; k0 += 32) {
        dma16(gAh + k0, lAh);
        dma16(gAl + k0, lAl);
        dma16(gBh + k0, lBh);
        dma16(gBl + k0, lBl);
        __syncthreads();

        half8 ah[2], av[2], bh[2], bv[2];
#pragma unroll
        for (int i = 0; i < 2; ++i) {
            int ar = wr * 32 + i * 16 + fr;
            ah[i] = *(const half8*)&sAh[ar * LDKE + fk];
            av[i] = *(const half8*)&sAl[ar * LDKE + fk];
            int bc = wc * 32 + i * 16 + fr;
            bh[i] = *(const half8*)&sBh[bc * LDKE + fk];
            bv[i] = *(const half8*)&sBl[bc * LDKE + fk];
        }
#pragma unroll
        for (int i = 0; i < 2; ++i)
#pragma unroll
            for (int j = 0; j < 2; ++j) {
                acc[i][j] = __builtin_amdgcn_mfma_f32_16x16x32_f16(ah[i], bh[j], acc[i][j], 0, 0, 0);
                acc[i][j] = __builtin_amdgcn_mfma_f32_16x16x32_f16(ah[i], bv[j], acc[i][j], 0, 0, 0);
                acc[i][j] = __builtin_amdgcn_mfma_f32_16x16x32_f16(av[i], bh[j], acc[i][j], 0, 0, 0);
            }
        __syncthreads();
    }

    int rbase = (lane >> 4) * 4;
#pragma unroll
    for (int i = 0; i < 2; ++i)
#pragma unroll
        for (int j = 0; j < 2; ++j) {
            int col = n0 + wc * 32 + j * 16 + fr;
#pragma unroll
            for (int r = 0; r < 4; ++r) {
                int row = m0 + wr * 32 + i * 16 + rbase + r;
                float v = acc[i][j][r];
                if (mode == 0) {
                    Cout[(size_t)row * N + col] = v;
                } else {
                    float f = fmaxf(v + bias[col], 0.0f);
                    _Float16 hh = (_Float16)f;
                    outH[(size_t)row * N + col] = hh;
                    outL[(size_t)row * N + col] = (_Float16)(f - (float)hh);
                }
            }
        }
}

// ---------------------------------------------------------------------------
// fp32 split-K GEMM (fallback path only)
// ---------------------------------------------------------------------------
__global__ __launch_bounds__(256) void gemm_splitk_k(const float* __restrict__ A,
                                                     const float* __restrict__ B,
                                                     const float* __restrict__ abias,
                                                     float* __restrict__ Cacc,
                                                     int M, int N, int K, int Kc)
{
    __shared__ float Ast[16][68];
    __shared__ float Bs[16][68];

    int m0 = blockIdx.y * 64, n0 = blockIdx.x * 64;
    int kb = blockIdx.z * Kc;
    int ke = min(K, kb + Kc);
    int tid = threadIdx.x;
    int tx = tid & 15, ty = tid >> 4;
    int arow = tid >> 2, akq = (tid & 3) << 2;
    int bcol = tid & 63, bk = tid >> 6;

    const float* Arow = A + (size_t)(m0 + arow) * K;
    bool nfull = (n0 + 64 <= N);

    float acc[4][4] = {};

    for (int k0 = kb; k0 < ke; k0 += 16) {
        float4 av = *(const float4*)(Arow + k0 + akq);
        if (abias) {
            av.x = fmaxf(av.x + abias[k0 + akq + 0], 0.0f);
            av.y = fmaxf(av.y + abias[k0 + akq + 1], 0.0f);
            av.z = fmaxf(av.z + abias[k0 + akq + 2], 0.0f);
            av.w = fmaxf(av.w + abias[k0 + akq + 3], 0.0f);
        }
        float bv[4];
        if (nfull) {
#pragma unroll
            for (int e = 0; e < 4; ++e)
                bv[e] = B[(size_t)(k0 + bk * 4 + e) * N + n0 + bcol];
        } else {
            bool ok = (n0 + bcol) < N;
#pragma unroll
            for (int e = 0; e < 4; ++e)
                bv[e] = ok ? B[(size_t)(k0 + bk * 4 + e) * N + n0 + bcol] : 0.0f;
        }
        __syncthreads();
        Ast[akq + 0][arow] = av.x;
        Ast[akq + 1][arow] = av.y;
        Ast[akq + 2][arow] = av.z;
        Ast[akq + 3][arow] = av.w;
#pragma unroll
        for (int e = 0; e < 4; ++e) Bs[bk * 4 + e][bcol] = bv[e];
        __syncthreads();

#pragma unroll
        for (int kk = 0; kk < 16; ++kk) {
            float4 af = *(const float4*)&Ast[kk][ty * 4];
            float4 bf = *(const float4*)&Bs[kk][tx * 4];
            float a_[4] = {af.x, af.y, af.z, af.w};
            float b_[4] = {bf.x, bf.y, bf.z, bf.w};
#pragma unroll
            for (int i = 0; i < 4; ++i)
#pragma unroll
                for (int j = 0; j < 4; ++j)
                    acc[i][j] = fmaf(a_[i], b_[j], acc[i][j]);
        }
    }

#pragma unroll
    for (int i = 0; i < 4; ++i) {
        int row = m0 + ty * 4 + i;
#pragma unroll
        for (int j = 0; j < 4; ++j) {
            int col = n0 + tx * 4 + j;
            if (col < N) atomicAdd(&Cacc[(size_t)row * N + col], acc[i][j]);
        }
    }
}

// ---------------------------------------------------------------------------
// softmax over (logits + bc), classes 1..80. grid = R, block = 64.
// ---------------------------------------------------------------------------
__global__ void softmax_k(const float* __restrict__ logits, int ldl,
                          const float* __restrict__ bc,
                          float* __restrict__ scr)
{
    int r = blockIdx.x;
    int t = threadIdx.x;
    const float* row = logits + (size_t)r * ldl;

    float v0 = row[t] + bc[t];
    float v1 = (t + 64 < NCLS) ? (row[t + 64] + bc[t + 64]) : -INFINITY;
    float m = fmaxf(v0, v1);
#pragma unroll
    for (int o = 32; o > 0; o >>= 1) m = fmaxf(m, __shfl_down(m, o));
    m = __shfl(m, 0);

    float e0 = expf(v0 - m);
    float e1 = (t + 64 < NCLS) ? expf(v1 - m) : 0.0f;
    float sum = e0 + e1;
#pragma unroll
    for (int o = 32; o > 0; o >>= 1) sum += __shfl_down(sum, o);
    sum = __shfl(sum, 0);
    float inv = 1.0f / sum;

    if (t >= 1)        scr[(size_t)r * DCLS + (t - 1)]  = e0 * inv;
    if (t + 64 < NCLS) scr[(size_t)r * DCLS + (t + 63)] = e1 * inv;
}

// ---------------------------------------------------------------------------
// per-image NMS with fused box decode. grid = n, block = 1024.
// ---------------------------------------------------------------------------
#define NMS_T 1024
__global__ __launch_bounds__(NMS_T) void nms_k(
    const float* __restrict__ scr,
    const float* __restrict__ prop,
    const int* __restrict__ imidx,
    const float* __restrict__ head, int ldh, int regofs,
    const float* __restrict__ br,
    const float* __restrict__ imsz,
    const float* __restrict__ score_thr_p,
    const float* __restrict__ min_size_p,
    const float* __restrict__ iou_thr_p,
    int* __restrict__ cidx,
    float* __restrict__ cscore,
    float* __restrict__ cbo,
    float* __restrict__ cbox,
    float* __restrict__ carea,
    float* __restrict__ out,
    int M, int n, int imtop)
{
    int img = blockIdx.x;
    int t = threadIdx.x;
    const int T = NMS_T;

    __shared__ int cnt;
    __shared__ float rs[NMS_T];
    __shared__ int rg[NMS_T];
    __shared__ int rl[NMS_T];
    __shared__ float wb0, wb1, wb2, wb3, wa;

    if (t == 0) cnt = 0;
    __syncthreads();

    float score_thr = score_thr_p[0];
    float min_size  = min_size_p[0];
    float iou_thr   = iou_thr_p[0];
    float immax = imsz[0];
    for (int q = 1; q < 2 * n; ++q) immax = fmaxf(immax, imsz[q]);

    int base = img * M;
    for (int j = t; j < M; j += T) {
        int r = j / DCLS;
        if (imidx[r] != img) continue;
        float s = scr[j];
        if (s <= score_thr) continue;

        int cls = j - r * DCLS + 1;
        const float* pr = prop + (size_t)r * 4;
        float pw = pr[2] - pr[0], ph = pr[3] - pr[1];
        float cx = (pr[0] + pr[2]) * 0.5f, cy = (pr[1] + pr[3]) * 0.5f;
        const float* rg_ = head + (size_t)r * ldh + regofs + cls * 4;
        const float* bb = br + cls * 4;
        float dx = (rg_[0] + bb[0]) * 0.1f;
        float dy = (rg_[1] + bb[1]) * 0.1f;
        float dw = fminf((rg_[2] + bb[2]) * 0.2f, FLOG_MAX);
        float dh = fminf((rg_[3] + bb[3]) * 0.2f, FLOG_MAX);
        float ncx = dx * pw + cx;
        float ncy = dy * ph + cy;
        float nw = expf(dw) * pw;
        float nh = expf(dh) * ph;
        float hbound = imsz[img * 2 + 0];
        float wbound = imsz[img * 2 + 1];
        float bx1 = fminf(fmaxf(ncx - nw * 0.5f, 0.0f), wbound);
        float bx2 = fminf(fmaxf(ncx + nw * 0.5f, 0.0f), wbound);
        float by1 = fminf(fmaxf(ncy - nh * 0.5f, 0.0f), hbound);
        float by2 = fminf(fmaxf(ncy + nh * 0.5f, 0.0f), hbound);
        if (bx2 - bx1 < min_size || by2 - by1 < min_size) continue;

        float off = (float)cls * (immax + 2.0f);
        int p = atomicAdd(&cnt, 1);
        cidx[base + p] = j;
        cscore[base + p] = s;
        cbox[(size_t)(base + p) * 4 + 0] = bx1;
        cbox[(size_t)(base + p) * 4 + 1] = by1;
        cbox[(size_t)(base + p) * 4 + 2] = bx2;
        cbox[(size_t)(base + p) * 4 + 3] = by2;
        cbo[(size_t)(base + p) * 4 + 0] = bx1 + off;
        cbo[(size_t)(base + p) * 4 + 1] = by1 + off;
        cbo[(size_t)(base + p) * 4 + 2] = bx2 + off;
        cbo[(size_t)(base + p) * 4 + 3] = by2 + off;
        carea[base + p] = (bx2 - bx1) * (by2 - by1);
    }
    __syncthreads();
    int K = cnt;

    float* ob  = out;
    float* osc = out + (size_t)n * imtop * 4;
    float* ocl = out + (size_t)n * imtop * 5;

    int it = 0;
    for (; it < imtop; ++it) {
        float best = -1e30f; int bg = 0x7fffffff; int bl = -1;
        for (int p = t; p < K; p += T) {
            float sv = cscore[base + p];
            int g = cidx[base + p];
            if (sv > best || (sv == best && g < bg)) { best = sv; bg = g; bl = p; }
        }
        rs[t] = best; rg[t] = bg; rl[t] = bl;
        __syncthreads();
        for (int o = T / 2; o > 0; o >>= 1) {
            if (t < o) {
                if (rs[t + o] > rs[t] || (rs[t + o] == rs[t] && rg[t + o] < rg[t])) {
                    rs[t] = rs[t + o]; rg[t] = rg[t + o]; rl[t] = rl[t + o];
                }
            }
            __syncthreads();
        }
        float s = rs[0]; int g = rg[0]; int lp = rl[0];
        if (s <= 0.0f) break;

        if (t == 0) {
            size_t oslot = (size_t)img * imtop + it;
            ob[oslot * 4 + 0] = cbox[(size_t)(base + lp) * 4 + 0];
            ob[oslot * 4 + 1] = cbox[(size_t)(base + lp) * 4 + 1];
            ob[oslot * 4 + 2] = cbox[(size_t)(base + lp) * 4 + 2];
            ob[oslot * 4 + 3] = cbox[(size_t)(base + lp) * 4 + 3];
            osc[oslot] = s;
            ocl[oslot] = (float)(g % DCLS + 1);
            wb0 = cbo[(size_t)(base + lp) * 4 + 0];
            wb1 = cbo[(size_t)(base + lp) * 4 + 1];
            wb2 = cbo[(size_t)(base + lp) * 4 + 2];
            wb3 = cbo[(size_t)(base + lp) * 4 + 3];
            wa  = carea[base + lp];
            cscore[base + lp] = -1.0f;
        }
        __syncthreads();
        float b0 = wb0, b1 = wb1, b2 = wb2, b3 = wb3, ai = wa;
        for (int p = t; p < K; p += T) {
            float c0 = cbo[(size_t)(base + p) * 4 + 0];
            float c1 = cbo[(size_t)(base + p) * 4 + 1];
            float c2 = cbo[(size_t)(base + p) * 4 + 2];
            float c3 = cbo[(size_t)(base + p) * 4 + 3];
            float iw = fmaxf(fminf(b2, c2) - fmaxf(b0, c0), 0.0f);
            float ih = fmaxf(fminf(b3, c3) - fmaxf(b1, c1), 0.0f);
            float inter = iw * ih;
            float iou = inter / (ai + carea[base + p] - inter + 1e-6f);
            if (iou > iou_thr) cscore[base + p] = -1.0f;
        }
        __syncthreads();
    }

    for (int q = it + t; q < imtop; q += T) {
        size_t oslot = (size_t)img * imtop + q;
        ob[oslot * 4 + 0] = 0.0f;
        ob[oslot * 4 + 1] = 0.0f;
        ob[oslot * 4 + 2] = 0.0f;
        ob[oslot * 4 + 3] = 0.0f;
        osc[oslot] = 0.0f;
        ocl[oslot] = -1.0f;
    }
}

// ---------------------------------------------------------------------------
extern "C" void kernel_launch(void* const* d_in, const int* in_sizes, int n_in,
                              void* d_out, int out_size, void* d_ws, size_t ws_size,
                              hipStream_t stream)
{
    const float* prop   = (const float*)d_in[0];
    const int*   imidx  = (const int*)d_in[1];
    const float* f0     = (const float*)d_in[2];
    const float* f1     = (const float*)d_in[3];
    const float* f2     = (const float*)d_in[4];
    const float* f3     = (const float*)d_in[5];
    const float* W0     = (const float*)d_in[6];
    const float* b0     = (const float*)d_in[7];
    const float* W1     = (const float*)d_in[8];
    const float* b1     = (const float*)d_in[9];
    const float* Wc     = (const float*)d_in[10];
    const float* bc     = (const float*)d_in[11];
    const float* Wr     = (const float*)d_in[12];
    const float* br     = (const float*)d_in[13];
    const float* imsz   = (const float*)d_in[14];
    const float* sthr   = (const float*)d_in[15];
    const float* ithr   = (const float*)d_in[16];
    const float* msz    = (const float*)d_in[18];

    int R = in_sizes[1];              // 1024
    int n = in_sizes[14] / 2;         // 2
    int imtop = out_size / (n * 6);   // 100
    int M = R * DCLS;                 // 81920
    int K0 = NPOOL * NPOOL * CCH;     // 12544
    int CL = in_sizes[7];             // 1024

    int h0 = (int)(sqrtf((float)(in_sizes[2] / (n * CCH))) + 0.5f);
    int h1 = (int)(sqrtf((float)(in_sizes[3] / (n * CCH))) + 0.5f);
    int h2 = (int)(sqrtf((float)(in_sizes[4] / (n * CCH))) + 0.5f);
    int h3 = (int)(sqrtf((float)(in_sizes[5] / (n * CCH))) + 0.5f);

    float* outf = (float*)d_out;

    // ---- MFMA-path workspace layout (bytes) ----
    size_t szPool  = (size_t)R * K0 * 2;
    size_t szX     = (size_t)R * CL * 4;
    size_t szHead  = (size_t)R * NHEAD * 4;
    size_t szWh    = (size_t)NHEAD * CL * 2;
    size_t szXh    = (size_t)R * CL * 2;
    size_t szW1t   = (size_t)CL * CL * 2;
    size_t szScr   = (size_t)R * DCLS * 4;

    size_t needed = 4 * szPool + 2 * szX + szHead + 2 * szWh
                  + 4 * szXh + 2 * szW1t + szScr;

    int splitK0 = 8;                  // Kc = K0/8 = 1568 = 49*32
    bool mfma_ok = (ws_size >= needed) && (R % 128 == 0) && (CL % 128 == 0)
                 && (K0 % (splitK0 * 32) == 0) && (CL % 32 == 0)
                 && ((R * 49) % 4 == 0);

    if (mfma_ok) {
        uint8_t* w = (uint8_t*)d_ws;
        size_t o = 0;
        _Float16* poolH   = (_Float16*)(w + o); o += szPool;
        _Float16* poolL   = (_Float16*)(w + o); o += szPool;
        _Float16* W0tH    = (_Float16*)(w + o); o += szPool;
        _Float16* W0tL    = (_Float16*)(w + o); o += szPool;
        float*    x0acc   = (float*)(w + o);    o += szX;
        float*    unused  = (float*)(w + o);    o += szX;   // (kept for layout stability)
        float*    headacc = (float*)(w + o);    o += szHead;
        _Float16* WheadtH = (_Float16*)(w + o); o += szWh;
        _Float16* WheadtL = (_Float16*)(w + o); o += szWh;
        _Float16* x0H     = (_Float16*)(w + o); o += szXh;
        _Float16* x0L     = (_Float16*)(w + o); o += szXh;
        _Float16* x1H     = (_Float16*)(w + o); o += szXh;
        _Float16* x1L     = (_Float16*)(w + o); o += szXh;
        _Float16* W1tH    = (_Float16*)(w + o); o += szW1t;
        _Float16* W1tL    = (_Float16*)(w + o); o += szW1t;
        float*    scr     = (float*)(w + o);
        (void)unused;

        // NMS compaction arrays alias the pool region (dead after FC0)
        int*   cidx   = (int*)d_ws;
        float* cscore = (float*)(cidx + (size_t)n * M);
        float* cbo    = cscore + (size_t)n * M;
        float* cbox   = cbo + (size_t)n * M * 4;
        float* carea  = cbox + (size_t)n * M * 4;

        // 0. zero only the split-K accumulator (x0acc, 4 MB)
        {
            int c4 = (int)(szX / 16);
            zero_k<<<dim3((c4 + 255) / 256), dim3(256), 0, stream>>>((float4*)x0acc, c4);
        }
        // 1. weight converts
        convert_w_t_k<<<dim3(K0 / 64, CL / 64), dim3(256), 0, stream>>>(W0, W0tH, W0tL, K0, CL);
        convert_w_t_k<<<dim3(CL / 64, CL / 64), dim3(256), 0, stream>>>(W1, W1tH, W1tL, CL, CL);
        convert_w_t_guard_k<<<dim3(CL / 64, (NCLS + 63) / 64), dim3(256), 0, stream>>>(
            Wc, WheadtH, WheadtL, CL, NCLS, CL, 0);
        convert_w_t_guard_k<<<dim3(CL / 64, (NCLS * 4 + 63) / 64), dim3(256), 0, stream>>>(
            Wr, WheadtH, WheadtL, CL, NCLS * 4, CL, NCLS);
        // 2. RoI align -> f16 hi/lo pooled (4 cells per 256-thr block)
        roi_align_f16v4_k<<<dim3(R * 49 / 4), dim3(256), 0, stream>>>(
            prop, imidx, f0, f1, f2, f3, h0, h1, h2, h3, poolH, poolL);
        // 3. FC0: x0acc = pooled @ W0  (split-K 8, XCD-pinned 1-D grid of 512)
        gemm_mfma_split_k<<<dim3(splitK0 * (R / 128) * (CL / 128)), dim3(256), 0, stream>>>(
            poolH, poolL, W0tH, W0tL, x0acc, R, CL, K0, K0 / splitK0, splitK0);
        // 4. x0 = relu(x0acc + b0) -> hi/lo
        act_split_k<<<dim3((R * CL / 4 + 255) / 256), dim3(256), 0, stream>>>(
            x0acc, b0, x0H, x0L, R * CL, CL);
        // 5. FC1 fused: x1 = relu(x0 @ W1 + b1) -> hi/lo directly (no atomics)
        gemm_mfma_fused64_k<<<dim3(CL / 64, R / 64), dim3(256), 0, stream>>>(
            x0H, x0L, W1tH, W1tL, b1, nullptr, x1H, x1L, R, CL, CL, 1);
        // 6. combined heads fused: headacc = x1 @ [Wc|Wr] raw fp32 (N=512)
        gemm_mfma_fused64_k<<<dim3(NHEAD / 64, R / 64), dim3(256), 0, stream>>>(
            x1H, x1L, WheadtH, WheadtL, nullptr, headacc, nullptr, nullptr, R, NHEAD, CL, 0);
        // 7. softmax (+bc)
        softmax_k<<<dim3(R), dim3(64), 0, stream>>>(headacc, NHEAD, bc, scr);
        // 8. NMS with fused decode (+br)
        nms_k<<<dim3(n), dim3(NMS_T), 0, stream>>>(
            scr, prop, imidx, headacc, NHEAD, NCLS, br, imsz, sthr, msz, ithr,
            cidx, cscore, cbo, cbox, carea, outf, M, n, imtop);
    } else {
        // -------- fallback: all-fp32 pipeline --------
        float* ws = (float*)d_ws;
        size_t off = 0;
        float* pooled  = ws + off; off += (size_t)R * K0;
        float* x0acc   = ws + off; off += (size_t)R * CL;
        float* x1acc   = ws + off; off += (size_t)R * CL;
        float* logits  = ws + off; off += (size_t)R * NCLS;
        off = (off + 3) & ~(size_t)3;
        float* reg     = ws + off; off += (size_t)R * NCLS * 4;
        float* scr     = ws + off; off += (size_t)R * DCLS;

        int*   cidx   = (int*)ws;
        float* cscore = (float*)(cidx + (size_t)n * M);
        float* cbo    = cscore + (size_t)n * M;
        float* cbox   = cbo + (size_t)n * M * 4;
        float* carea  = cbox + (size_t)n * M * 4;

        {
            size_t zcount = (size_t)(reg + (size_t)R * NCLS * 4 - x0acc);
            int c4 = (int)(zcount / 4);
            zero_k<<<dim3((c4 + 255) / 256), dim3(256), 0, stream>>>((float4*)x0acc, c4);
        }
        roi_align_k<<<dim3(R * 49), dim3(256), 0, stream>>>(
            prop, imidx, f0, f1, f2, f3, h0, h1, h2, h3, pooled);
        gemm_splitk_k<<<dim3(CL / 64, R / 64, 8), dim3(256), 0, stream>>>(
            pooled, W0, nullptr, x0acc, R, CL, K0, 1568);
        gemm_splitk_k<<<dim3(CL / 64, R / 64, 4), dim3(256), 0, stream>>>(
            x0acc, W1, b0, x1acc, R, CL, CL, 256);
        gemm_splitk_k<<<dim3((NCLS + 63) / 64, R / 64, 8), dim3(256), 0, stream>>>(
            x1acc, Wc, b1, logits, R, NCLS, CL, 128);
        gemm_splitk_k<<<dim3((NCLS * 4 + 63) / 64, R / 64, 4), dim3(256), 0, stream>>>(
            x1acc, Wr, b1, reg, R, NCLS * 4, CL, 256);
        softmax_k<<<dim3(R), dim3(64), 0, stream>>>(logits, NCLS, bc, scr);
        nms_k<<<dim3(n), dim3(NMS_T), 0, stream>>>(
            scr, prop, imidx, reg, NCLS * 4, 0, br, imsz, sthr, msz, ithr,
            cidx, cscore, cbo, cbox, carea, outf, M, n, imtop);
    }
}